// Round 1
// baseline (305.277 us; speedup 1.0000x reference)
//
#include <hip/hip_runtime.h>

typedef __bf16 bf16x8 __attribute__((ext_vector_type(8)));
typedef float f32x4 __attribute__((ext_vector_type(4)));
typedef unsigned short u16;
typedef unsigned int u32;

#define BATCH 8
#define TLEN 512
#define DMODEL 512
#define NH 8
#define DH 64
#define MEMLEN 512
#define CMEMLEN 128
#define KVLEN 1152
#define TOTALMEM 640
#define ATT_SCALE 0.125f

__device__ inline u16 f2b(float f) {
    union { float f; u32 u; } x; x.f = f;
    u32 u = x.u;
    return (u16)((u + 0x7FFFu + ((u >> 16) & 1u)) >> 16);
}

__device__ inline float wave_red_sum(float v) {
#pragma unroll
    for (int off = 1; off < 64; off <<= 1) v += __shfl_xor(v, off);
    return v;
}

// ---------------- converts ----------------
__global__ __launch_bounds__(256) void cvt_f32_bf16(const float* __restrict__ in,
                                                    u16* __restrict__ out, int n) {
    int i = (blockIdx.x * 256 + threadIdx.x) * 4;
    if (i < n) {
        float4 v = *(const float4*)(in + i);
        out[i + 0] = f2b(v.x); out[i + 1] = f2b(v.y);
        out[i + 2] = f2b(v.z); out[i + 3] = f2b(v.w);
    }
}

__global__ __launch_bounds__(256) void build_kvin(const float* __restrict__ x,
                                                  const float* __restrict__ mem,
                                                  const float* __restrict__ cmem,
                                                  u16* __restrict__ out) {
    int idx = blockIdx.x * 256 + threadIdx.x;     // 9216*512 elements
    int row = idx >> 9, col = idx & 511;
    int b = row / KVLEN;
    int p = row - b * KVLEN;
    float v;
    if (p < CMEMLEN)              v = cmem[(b * CMEMLEN + p) * DMODEL + col];
    else if (p < CMEMLEN + MEMLEN) v = mem[(b * MEMLEN + (p - CMEMLEN)) * DMODEL + col];
    else                           v = x[(b * TLEN + (p - TOTALMEM)) * DMODEL + col];
    out[idx] = f2b(v);
}

// conv_w (O=512, I=512, T=4) -> W2[o][t*512+i]
__global__ __launch_bounds__(256) void build_convw2(const float* __restrict__ cw,
                                                    u16* __restrict__ out) {
    int idx = blockIdx.x * 256 + threadIdx.x;     // 512*2048
    int o = idx >> 11, rem = idx & 2047;
    int t = rem >> 9, i = rem & 511;
    out[idx] = f2b(cw[o * 2048 + i * 4 + t]);
}

__global__ void zero2(float* a) { if (threadIdx.x < 2) a[threadIdx.x] = 0.f; }

// ---------------- generic bf16 MFMA GEMM: C = A(M,K) * B^T(N,K) (+bias) ----------------
__global__ __launch_bounds__(256)
void gemm_bt(const u16* __restrict__ A, int lda,
             const u16* __restrict__ Bt, int ldb,
             int K,
             float* __restrict__ Cf, u16* __restrict__ Cb, int ldc,
             const float* __restrict__ bias) {
    __shared__ u16 As[128 * 40];
    __shared__ u16 Bs[128 * 40];
    const int tid = threadIdx.x;
    const int srow = tid >> 1, scol = (tid & 1) * 16;
    const int lane = tid & 63, wave = tid >> 6;
    const int wr = (wave >> 1) * 64, wc = (wave & 1) * 64;
    const int fr = lane & 15, fg = lane >> 4;
    const int arow0 = blockIdx.x * 128;
    const int brow0 = blockIdx.y * 128;
    f32x4 acc[4][4] = {};

    for (int k0 = 0; k0 < K; k0 += 32) {
        __syncthreads();
        const u16* ga = A + (size_t)(arow0 + srow) * lda + k0 + scol;
        const u16* gb = Bt + (size_t)(brow0 + srow) * ldb + k0 + scol;
        *(bf16x8*)&As[srow * 40 + scol]     = *(const bf16x8*)ga;
        *(bf16x8*)&As[srow * 40 + scol + 8] = *(const bf16x8*)(ga + 8);
        *(bf16x8*)&Bs[srow * 40 + scol]     = *(const bf16x8*)gb;
        *(bf16x8*)&Bs[srow * 40 + scol + 8] = *(const bf16x8*)(gb + 8);
        __syncthreads();
        bf16x8 af[4], bfr[4];
#pragma unroll
        for (int m = 0; m < 4; ++m) af[m] = *(bf16x8*)&As[(wr + m * 16 + fr) * 40 + fg * 8];
#pragma unroll
        for (int n = 0; n < 4; ++n) bfr[n] = *(bf16x8*)&Bs[(wc + n * 16 + fr) * 40 + fg * 8];
#pragma unroll
        for (int m = 0; m < 4; ++m)
#pragma unroll
            for (int n = 0; n < 4; ++n)
                acc[m][n] = __builtin_amdgcn_mfma_f32_16x16x32_bf16(af[m], bfr[n], acc[m][n], 0, 0, 0);
    }

#pragma unroll
    for (int m = 0; m < 4; ++m)
#pragma unroll
        for (int n = 0; n < 4; ++n)
#pragma unroll
            for (int r = 0; r < 4; ++r) {
                int row = arow0 + wr + m * 16 + fg * 4 + r;
                int col = brow0 + wc + n * 16 + fr;
                float v = acc[m][n][r];
                if (bias) v += bias[col];
                if (Cf) Cf[(size_t)row * ldc + col] = v;
                if (Cb) Cb[(size_t)row * ldc + col] = f2b(v);
            }
}

// ---------------- V transpose: kv[(b*rows+j)*1024 + 512 + h*64 + dh] -> vT[(bh*64+dh)*rows + j]
__global__ __launch_bounds__(256)
void transpose_v(const u16* __restrict__ kv, u16* __restrict__ vT, int rowsPerB) {
    int jt = blockIdx.x, bh = blockIdx.y;
    int b = bh >> 3, h = bh & 7;
    __shared__ u16 t_s[64 * 65];
    int tid = threadIdx.x;
    int jr = tid >> 2, c0 = (tid & 3) * 16;
    const u16* g = kv + (size_t)(b * rowsPerB + jt * 64 + jr) * 1024 + 512 + h * DH + c0;
#pragma unroll
    for (int u = 0; u < 16; ++u) t_s[jr * 65 + c0 + u] = g[u];
    __syncthreads();
    int dh = tid >> 2, j0 = (tid & 3) * 16;
    union { u16 us[8]; bf16x8 v8; } o1, o2;
#pragma unroll
    for (int u = 0; u < 8; ++u) {
        o1.us[u] = t_s[(j0 + u) * 65 + dh];
        o2.us[u] = t_s[(j0 + 8 + u) * 65 + dh];
    }
    u16* o = vT + (size_t)(bh * DH + dh) * rowsPerB + jt * 64 + j0;
    *(bf16x8*)o = o1.v8;
    *(bf16x8*)(o + 8) = o2.v8;
}

// ---------------- flash attention (MODE0 main causal, MODE1 aux-mem, MODE2 aux-cmem+diff)
template <int MODE>
__global__ __launch_bounds__(256)
void attn_kernel(const u16* __restrict__ q_bf,
                 const u16* __restrict__ kmat,
                 const u16* __restrict__ vT,
                 u16* __restrict__ out_bf,
                 float* __restrict__ out_f32,
                 float* __restrict__ acc_sum) {
    const int it = blockIdx.x;
    const int bh = blockIdx.y;
    const int b = bh >> 3, h = bh & 7;
    const int ib = it * 32;
    const int tid = threadIdx.x;
    const int lane = tid & 63, wave = tid >> 6;

    constexpr int KROWS = (MODE == 2) ? CMEMLEN : KVLEN;
    constexpr int KOFF = (MODE == 1) ? 128 : 0;
    constexpr int NJT_FIX = (MODE == 1) ? 8 : 2;

    __shared__ u16 q_s[32 * 72];
    __shared__ u16 k_s[64 * 72];
    __shared__ u16 v_s[64 * 72];
    __shared__ float s_s[32 * 65];
    __shared__ u16 p_s[32 * 72];
    __shared__ float scale_s[32];
    __shared__ float l_s[32];
    __shared__ float red_s[4];

    {   // q tile 32x64
        int r = tid >> 3, c0 = (tid & 7) * 8;
        *(bf16x8*)&q_s[r * 72 + c0] =
            *(const bf16x8*)&q_bf[(size_t)(b * TLEN + ib + r) * DMODEL + h * DH + c0];
    }

    const int srow = tid >> 3, sc0 = (tid & 7) * 8;
    float m_run = -1e30f, l_run = 0.f;

    const int i0 = (wave >> 1) * 16;
    const int nb = (wave & 1) * 32;
    const int fr = lane & 15, fg = lane >> 4;
    f32x4 oacc[2] = {};

    int njt = (MODE == 0) ? (((ib + 671) >> 6) + 1) : NJT_FIX;

    for (int jt = 0; jt < njt; ++jt) {
        __syncthreads();
        {   // stage K tile [64j][64c] and vT tile [64dh][64j]
            int jr = tid >> 2, c0 = (tid & 3) * 16;
            const u16* gk = kmat + (size_t)(b * KROWS + KOFF + jt * 64 + jr) * 1024 + h * DH + c0;
            *(bf16x8*)&k_s[jr * 72 + c0]     = *(const bf16x8*)gk;
            *(bf16x8*)&k_s[jr * 72 + c0 + 8] = *(const bf16x8*)(gk + 8);
            const u16* gv = vT + (size_t)(bh * DH + jr) * KROWS + KOFF + jt * 64 + c0;
            *(bf16x8*)&v_s[jr * 72 + c0]     = *(const bf16x8*)gv;
            *(bf16x8*)&v_s[jr * 72 + c0 + 8] = *(const bf16x8*)(gv + 8);
        }
        __syncthreads();
        // QK^T -> s_s
#pragma unroll
        for (int u = 0; u < 2; ++u) {
            int j0 = nb + u * 16;
            f32x4 d = {};
#pragma unroll
            for (int kk = 0; kk < 2; ++kk) {
                bf16x8 aq = *(bf16x8*)&q_s[(i0 + fr) * 72 + kk * 32 + fg * 8];
                bf16x8 bk = *(bf16x8*)&k_s[(j0 + fr) * 72 + kk * 32 + fg * 8];
                d = __builtin_amdgcn_mfma_f32_16x16x32_bf16(aq, bk, d, 0, 0, 0);
            }
#pragma unroll
            for (int r = 0; r < 4; ++r) {
                int irow = i0 + fg * 4 + r;
                int jcol = j0 + fr;
                float sv = d[r] * ATT_SCALE;
                if (MODE == 0) {
                    int jg = jt * 64 + jcol;
                    int ig = ib + irow;
                    if (jg > ig + TOTALMEM) sv = -1e30f;
                }
                s_s[irow * 65 + jcol] = sv;
            }
        }
        __syncthreads();
        // online softmax: 8 threads per row
        {
            float v[8];
#pragma unroll
            for (int u = 0; u < 8; ++u) v[u] = s_s[srow * 65 + sc0 + u];
            float tmax = v[0];
#pragma unroll
            for (int u = 1; u < 8; ++u) tmax = fmaxf(tmax, v[u]);
            tmax = fmaxf(tmax, __shfl_xor(tmax, 1));
            tmax = fmaxf(tmax, __shfl_xor(tmax, 2));
            tmax = fmaxf(tmax, __shfl_xor(tmax, 4));
            float m_new = fmaxf(m_run, tmax);
            float scl = __expf(m_run - m_new);
            float psum = 0.f;
            union { u16 us[8]; bf16x8 v8; } pk;
#pragma unroll
            for (int u = 0; u < 8; ++u) {
                float p = __expf(v[u] - m_new);
                psum += p;
                pk.us[u] = f2b(p);
            }
            psum += __shfl_xor(psum, 1);
            psum += __shfl_xor(psum, 2);
            psum += __shfl_xor(psum, 4);
            l_run = l_run * scl + psum;
            m_run = m_new;
            *(bf16x8*)&p_s[srow * 72 + sc0] = pk.v8;
            if ((tid & 7) == 0) scale_s[srow] = scl;
        }
        __syncthreads();
        // rescale + PV
#pragma unroll
        for (int u = 0; u < 2; ++u)
#pragma unroll
            for (int r = 0; r < 4; ++r) oacc[u][r] *= scale_s[i0 + fg * 4 + r];
#pragma unroll
        for (int u = 0; u < 2; ++u) {
            int n0 = nb + u * 16;
#pragma unroll
            for (int kk = 0; kk < 2; ++kk) {
                bf16x8 ap = *(bf16x8*)&p_s[(i0 + fr) * 72 + kk * 32 + fg * 8];
                bf16x8 bv = *(bf16x8*)&v_s[(n0 + fr) * 72 + kk * 32 + fg * 8];
                oacc[u] = __builtin_amdgcn_mfma_f32_16x16x32_bf16(ap, bv, oacc[u], 0, 0, 0);
            }
        }
    }

    if ((tid & 7) == 0) l_s[srow] = l_run;
    __syncthreads();

    float lsum_local = 0.f;
#pragma unroll
    for (int u = 0; u < 2; ++u) {
        int n0 = nb + u * 16;
#pragma unroll
        for (int r = 0; r < 4; ++r) {
            int irow = i0 + fg * 4 + r;
            int ig = ib + irow;
            int dh = n0 + fr;
            float val = oacc[u][r] / l_s[irow];
            if (MODE == 0) {
                out_bf[(size_t)(b * TLEN + ig) * DMODEL + h * DH + dh] = f2b(val);
            } else if (MODE == 1) {
                out_f32[(size_t)(bh * TLEN + ig) * DH + dh] = val;
            } else {
                float df = val - out_f32[(size_t)(bh * TLEN + ig) * DH + dh];
                lsum_local += df * df;
            }
        }
    }
    if (MODE == 2) {
        lsum_local = wave_red_sum(lsum_local);
        if (lane == 0) red_s[wave] = lsum_local;
        __syncthreads();
        if (tid == 0) atomicAdd(acc_sum, red_s[0] + red_s[1] + red_s[2] + red_s[3]);
    }
}

// ---------------- ae loss: recon[b,m,dd] = sum_c cmem_new[b,c,dd]*dw[m,c] + db[m]
__global__ __launch_bounds__(256)
void ae_loss_kernel(const float* __restrict__ cmem_new,
                    const float* __restrict__ mem,
                    const float* __restrict__ dw,
                    const float* __restrict__ db,
                    float* __restrict__ acc) {
    int b = blockIdx.x >> 7;
    int m0 = (blockIdx.x & 127) * 4;
    __shared__ float w_s[4][128];
    __shared__ float red_s2[4];
    int tid = threadIdx.x;
    if (tid < 128) {
#pragma unroll
        for (int mm = 0; mm < 4; ++mm) w_s[mm][tid] = dw[(m0 + mm) * 128 + tid];
    }
    __syncthreads();
    float lsum = 0.f;
#pragma unroll
    for (int rep = 0; rep < 2; ++rep) {
        int dd = tid + rep * 256;
        float a0 = 0, a1 = 0, a2 = 0, a3 = 0;
        for (int c = 0; c < 128; ++c) {
            float cv = cmem_new[(size_t)b * 65536 + c * 512 + dd];
            a0 += cv * w_s[0][c]; a1 += cv * w_s[1][c];
            a2 += cv * w_s[2][c]; a3 += cv * w_s[3][c];
        }
#pragma unroll
        for (int mm = 0; mm < 4; ++mm) {
            float a = (mm == 0) ? a0 : (mm == 1) ? a1 : (mm == 2) ? a2 : a3;
            float d = mem[(size_t)(b * 512 + m0 + mm) * 512 + dd] - (a + db[m0 + mm]);
            lsum += d * d;
        }
    }
    lsum = wave_red_sum(lsum);
    if ((tid & 63) == 0) red_s2[tid >> 6] = lsum;
    __syncthreads();
    if (tid == 0) atomicAdd(acc, red_s2[0] + red_s2[1] + red_s2[2] + red_s2[3]);
}

__global__ void finalize(const float* __restrict__ acc, float* __restrict__ out) {
    if (threadIdx.x == 0) {
        out[0] = acc[0] * (1.f / 2097152.f);
        out[1] = acc[1] * (1.f / 2097152.f);
    }
}

// ---------------- launch ----------------
extern "C" void kernel_launch(void* const* d_in, const int* in_sizes, int n_in,
                              void* d_out, int out_size, void* d_ws, size_t ws_size,
                              hipStream_t stream) {
    const float* x      = (const float*)d_in[0];
    const float* mem    = (const float*)d_in[1];
    const float* cmem   = (const float*)d_in[2];
    const float* Wq     = (const float*)d_in[3];
    const float* Wkv    = (const float*)d_in[4];
    const float* Wo     = (const float*)d_in[5];
    const float* bo     = (const float*)d_in[6];
    const float* conv_w = (const float*)d_in[7];
    const float* conv_b = (const float*)d_in[8];
    const float* deconv_w = (const float*)d_in[9];
    const float* deconv_b = (const float*)d_in[10];
    float* out = (float*)d_out;

    char* w = (char*)d_ws;
    auto alloc = [&](size_t bytes) { char* p = w; w += (bytes + 255) & ~255ull; return p; };
    u16* Wq_bf   = (u16*)alloc(262144 * 2);
    u16* Wkv_bf  = (u16*)alloc(524288 * 2);
    u16* Wo_bf   = (u16*)alloc(262144 * 2);
    u16* mem_bf  = (u16*)alloc(2097152 * 2);
    u16* x_bf    = (u16*)alloc(2097152 * 2);
    u16* cw2_bf  = (u16*)alloc(1048576 * 2);
    u16* kvin_bf = (u16*)alloc(4718592 * 2);
    u16* q_bf    = (u16*)alloc(2097152 * 2);
    u16* kv_bf   = (u16*)alloc(9437184 * 2);
    u16* comp_bf = (u16*)alloc(524288 * 2);
    u16* ckv_bf  = (u16*)alloc(1048576 * 2);
    u16* vTm     = (u16*)alloc(4718592 * 2);
    u16* vTc     = (u16*)alloc(524288 * 2);
    u16* attn_bf = (u16*)alloc(2097152 * 2);
    float* out1  = (float*)alloc(2097152 * 4);
    float* accs  = (float*)alloc(256);

    float* logits_o  = out;
    float* newmem_o  = out + 2097152;
    float* newcmem_o = out + 4194304;
    float* scalars_o = out + 4718592;

    // converts + setup
    cvt_f32_bf16<<<256,  256, 0, stream>>>(Wq,  Wq_bf,  262144);
    cvt_f32_bf16<<<512,  256, 0, stream>>>(Wkv, Wkv_bf, 524288);
    cvt_f32_bf16<<<256,  256, 0, stream>>>(Wo,  Wo_bf,  262144);
    cvt_f32_bf16<<<2048, 256, 0, stream>>>(mem, mem_bf, 2097152);
    cvt_f32_bf16<<<2048, 256, 0, stream>>>(x,   x_bf,   2097152);
    build_kvin<<<18432, 256, 0, stream>>>(x, mem, cmem, kvin_bf);
    build_convw2<<<4096, 256, 0, stream>>>(conv_w, cw2_bf);
    zero2<<<1, 64, 0, stream>>>(accs);
    hipMemcpyAsync(newmem_o, x, 2097152 * sizeof(float), hipMemcpyDeviceToDevice, stream);

    // projections
    gemm_bt<<<dim3(32, 4), 256, 0, stream>>>(x_bf, 512, Wq_bf, 512, 512,
                                             nullptr, q_bf, 512, nullptr);
    gemm_bt<<<dim3(72, 8), 256, 0, stream>>>(kvin_bf, 512, Wkv_bf, 512, 512,
                                             nullptr, kv_bf, 1024, nullptr);
    transpose_v<<<dim3(18, 64), 256, 0, stream>>>(kv_bf, vTm, KVLEN);

    // conv compression (as GEMM) -> new_cmem (f32 out) + bf16 copy
    gemm_bt<<<dim3(8, 4), 256, 0, stream>>>(mem_bf, 2048, cw2_bf, 2048, 2048,
                                            newcmem_o, comp_bf, 512, conv_b);
    gemm_bt<<<dim3(8, 8), 256, 0, stream>>>(comp_bf, 512, Wkv_bf, 512, 512,
                                            nullptr, ckv_bf, 1024, nullptr);
    transpose_v<<<dim3(2, 64), 256, 0, stream>>>(ckv_bf, vTc, CMEMLEN);

    // main attention + output projection
    attn_kernel<0><<<dim3(16, 64), 256, 0, stream>>>(q_bf, kv_bf, vTm, attn_bf, nullptr, nullptr);
    gemm_bt<<<dim3(32, 4), 256, 0, stream>>>(attn_bf, 512, Wo_bf, 512, 512,
                                             logits_o, nullptr, 512, bo);

    // aux loss
    attn_kernel<1><<<dim3(16, 64), 256, 0, stream>>>(q_bf, kv_bf, vTm, nullptr, out1, nullptr);
    attn_kernel<2><<<dim3(16, 64), 256, 0, stream>>>(q_bf, ckv_bf, vTc, nullptr, out1, accs);

    // ae loss
    ae_loss_kernel<<<1024, 256, 0, stream>>>(newcmem_o, mem, deconv_w, deconv_b, accs + 1);

    finalize<<<1, 64, 0, stream>>>(accs, scalars_o);
}

// Round 2
// 293.236 us; speedup vs baseline: 1.0411x; 1.0411x over previous
//
#include <hip/hip_runtime.h>

typedef __bf16 bf16x8 __attribute__((ext_vector_type(8)));
typedef float f32x4 __attribute__((ext_vector_type(4)));
typedef unsigned short u16;
typedef unsigned int u32;
typedef unsigned long long u64;

#define TLEN 512
#define DMODEL 512
#define DH 64
#define KVLEN 1152
#define TOTALMEM 640
#define ATT_SCALE 0.125f

__device__ inline u16 f2b(float f) {
    union { float f; u32 u; } x; x.f = f;
    u32 u = x.u;
    return (u16)((u + 0x7FFFu + ((u >> 16) & 1u)) >> 16);
}

__device__ inline float wave_red_sum(float v) {
#pragma unroll
    for (int off = 1; off < 64; off <<= 1) v += __shfl_xor(v, off);
    return v;
}

__device__ inline void gload16(const u16* g, u16* l) {
    __builtin_amdgcn_global_load_lds((const __attribute__((address_space(1))) void*)g,
                                     (__attribute__((address_space(3))) void*)l, 16, 0, 0);
}

// ---------------- fused prep: kvin build + weight converts + convw permute + acc zero
// regions (element offsets): kvin [0,4718592) ; Wq +262144 ; Wkv +524288 ; Wo +262144 ; cw2 +1048576
__global__ __launch_bounds__(256)
void prep_kernel(const float* __restrict__ x, const float* __restrict__ mem,
                 const float* __restrict__ cmem, const float* __restrict__ Wq,
                 const float* __restrict__ Wkv, const float* __restrict__ Wo,
                 const float* __restrict__ cw,
                 u16* __restrict__ kvin, u16* __restrict__ wq_b, u16* __restrict__ wkv_b,
                 u16* __restrict__ wo_b, u16* __restrict__ cw2, float* __restrict__ accs) {
    int idx = blockIdx.x * 256 + threadIdx.x;
    if (idx == 0) { accs[0] = 0.f; accs[1] = 0.f; }
    int e = idx * 4;
    float4 v;
    u16* o;
    if (e < 4718592) {
        int row = e >> 9, col = e & 511;
        int b = row / KVLEN, p = row - b * KVLEN;
        const float* src;
        if (p < 128)       src = cmem + ((size_t)(b * 128 + p)) * 512 + col;
        else if (p < 640)  src = mem  + ((size_t)(b * 512 + (p - 128))) * 512 + col;
        else               src = x    + ((size_t)(b * 512 + (p - 640))) * 512 + col;
        v = *(const float4*)src; o = kvin + e;
    } else if (e < 4980736) {
        int t = e - 4718592; v = *(const float4*)(Wq + t); o = wq_b + t;
    } else if (e < 5505024) {
        int t = e - 4980736; v = *(const float4*)(Wkv + t); o = wkv_b + t;
    } else if (e < 5767168) {
        int t = e - 5505024; v = *(const float4*)(Wo + t); o = wo_b + t;
    } else {
        int t = e - 5767168;
        int oo = t >> 11, rem = t & 2047, tt = rem >> 9, ii = rem & 511;
        const float* s0 = cw + oo * 2048 + tt;
        v.x = s0[(ii + 0) * 4]; v.y = s0[(ii + 1) * 4];
        v.z = s0[(ii + 2) * 4]; v.w = s0[(ii + 3) * 4];
        o = cw2 + t;
    }
    o[0] = f2b(v.x); o[1] = f2b(v.y); o[2] = f2b(v.z); o[3] = f2b(v.w);
}

// ---------------- generic bf16 MFMA GEMM (m97 staging): C = A(M,K)*B^T(N,K)
// A row m lives at A + (m/rowsPerB)*bstride + (m%rowsPerB)*lda  (elements)
// If Cpart != null: write f32 partial at Cpart[z*partStride + m*ldc + n] (split-K via gridDim.z)
__global__ __launch_bounds__(256)
void gemm_bt(const u16* __restrict__ A, int lda, int rowsPerB, long long bstride,
             const u16* __restrict__ Bt, int ldb, int Kb,
             float* __restrict__ Cpart, int partStride,
             float* __restrict__ Cf, u16* __restrict__ Cb, int ldc,
             const float* __restrict__ bias) {
    __shared__ u16 As[128 * 32];
    __shared__ u16 Bs[128 * 32];
    const int tid = threadIdx.x;
    const int lane = tid & 63, wave = tid >> 6;
    const int wr = (wave >> 1) * 64, wc = (wave & 1) * 64;
    const int fr = lane & 15, fg = lane >> 4;
    const int arow0 = blockIdx.x * 128;
    const int brow0 = blockIdx.y * 128;
    const int k0start = blockIdx.z * Kb;

    const int lrow = lane >> 2;          // 0..15
    const int lcol = (lane & 3) * 8;     // u16 offset within 32-wide k-slab
    const u16* gA[2]; const u16* gB[2];
#pragma unroll
    for (int i = 0; i < 2; ++i) {
        int r = wave * 32 + i * 16 + lrow;
        int gr = arow0 + r;
        int bb = gr / rowsPerB;
        int lr = gr - bb * rowsPerB;
        gA[i] = A + (size_t)bb * bstride + (size_t)lr * lda + k0start + lcol;
        gB[i] = Bt + (size_t)(brow0 + r) * ldb + k0start + lcol;
    }
    u16* lA0 = &As[(wave * 32) * 32];
    u16* lA1 = &As[(wave * 32 + 16) * 32];
    u16* lB0 = &Bs[(wave * 32) * 32];
    u16* lB1 = &Bs[(wave * 32 + 16) * 32];

    f32x4 acc[4][4] = {};
    for (int k = 0; k < Kb; k += 32) {
        __syncthreads();
        gload16(gA[0] + k, lA0);
        gload16(gA[1] + k, lA1);
        gload16(gB[0] + k, lB0);
        gload16(gB[1] + k, lB1);
        __syncthreads();
        bf16x8 af[4], bfr[4];
#pragma unroll
        for (int m = 0; m < 4; ++m) af[m] = *(bf16x8*)&As[(wr + m * 16 + fr) * 32 + fg * 8];
#pragma unroll
        for (int n = 0; n < 4; ++n) bfr[n] = *(bf16x8*)&Bs[(wc + n * 16 + fr) * 32 + fg * 8];
#pragma unroll
        for (int m = 0; m < 4; ++m)
#pragma unroll
            for (int n = 0; n < 4; ++n)
                acc[m][n] = __builtin_amdgcn_mfma_f32_16x16x32_bf16(af[m], bfr[n], acc[m][n], 0, 0, 0);
    }

#pragma unroll
    for (int m = 0; m < 4; ++m)
#pragma unroll
        for (int n = 0; n < 4; ++n)
#pragma unroll
            for (int r = 0; r < 4; ++r) {
                int row = arow0 + wr + m * 16 + fg * 4 + r;
                int col = brow0 + wc + n * 16 + fr;
                float v = acc[m][n][r];
                if (Cpart) {
                    Cpart[(size_t)blockIdx.z * partStride + (size_t)row * ldc + col] = v;
                } else {
                    if (bias) v += bias[col];
                    if (Cf) Cf[(size_t)row * ldc + col] = v;
                    if (Cb) Cb[(size_t)row * ldc + col] = f2b(v);
                }
            }
}

// ---------------- split-K reduce for conv: + bias, write f32 (new_cmem) + bf16 (comp)
__global__ __launch_bounds__(256)
void conv_reduce(const float* __restrict__ part, const float* __restrict__ cb,
                 float* __restrict__ outf, u16* __restrict__ outb) {
    int idx = (blockIdx.x * 256 + threadIdx.x) * 4;   // 524288 total
    float4 s = *(const float4*)(part + idx);
#pragma unroll
    for (int sp = 1; sp < 8; ++sp) {
        float4 p = *(const float4*)(part + (size_t)sp * 524288 + idx);
        s.x += p.x; s.y += p.y; s.z += p.z; s.w += p.w;
    }
    float4 bb = *(const float4*)(cb + (idx & 511));
    s.x += bb.x; s.y += bb.y; s.z += bb.z; s.w += bb.w;
    *(float4*)(outf + idx) = s;
    outb[idx + 0] = f2b(s.x); outb[idx + 1] = f2b(s.y);
    outb[idx + 2] = f2b(s.z); outb[idx + 3] = f2b(s.w);
}

// ---------------- V transpose: kv[(b*rows+j)*1024 + 512 + h*64 + dh] -> vT[(bh*64+dh)*rows + j]
__global__ __launch_bounds__(256)
void transpose_v(const u16* __restrict__ kv, u16* __restrict__ vT, int rowsPerB) {
    int jt = blockIdx.x, bh = blockIdx.y;
    int b = bh >> 3, h = bh & 7;
    __shared__ u16 t_s[64 * 65];
    int tid = threadIdx.x;
    int jr = tid >> 2, c0 = (tid & 3) * 16;
    const u16* g = kv + (size_t)(b * rowsPerB + jt * 64 + jr) * 1024 + 512 + h * DH + c0;
#pragma unroll
    for (int u = 0; u < 16; ++u) t_s[jr * 65 + c0 + u] = g[u];
    __syncthreads();
    int dh = tid >> 2, j0 = (tid & 3) * 16;
    union { u16 us[8]; bf16x8 v8; } o1, o2;
#pragma unroll
    for (int u = 0; u < 8; ++u) {
        o1.us[u] = t_s[(j0 + u) * 65 + dh];
        o2.us[u] = t_s[(j0 + 8 + u) * 65 + dh];
    }
    u16* o = vT + (size_t)(bh * DH + dh) * rowsPerB + jt * 64 + j0;
    *(bf16x8*)o = o1.v8;
    *(bf16x8*)(o + 8) = o2.v8;
}

// ---------------- attention shared state + non-causal phase helper
struct AttnShared {
    u16 q_s[32 * 72];
    u16 k_s[64 * 72];
    u16 v_s[64 * 72];
    float s_s[32 * 65];
    u16 p_s[32 * 72];
    float scale_s[32];
    float l_s[32];
    float red_s[4];
};

__device__ inline void attn_nc_phase(AttnShared& sh,
                                     const u16* __restrict__ kmat, const u16* __restrict__ vT,
                                     int krows, int koff, int njt,
                                     int b, int bh, int h, int tid, f32x4 out[2]) {
    const int lane = tid & 63, wave = tid >> 6;
    const int srow = tid >> 3, sc0 = (tid & 7) * 8;
    const int i0 = (wave >> 1) * 16;
    const int nb = (wave & 1) * 32;
    const int fr = lane & 15, fg = lane >> 4;
    float m_run = -1e30f, l_run = 0.f;
    f32x4 oacc[2] = {};

    for (int jt = 0; jt < njt; ++jt) {
        __syncthreads();
        {
            int jr = tid >> 2, c0 = (tid & 3) * 16;
            const u16* gk = kmat + (size_t)(b * krows + koff + jt * 64 + jr) * 1024 + h * DH + c0;
            *(bf16x8*)&sh.k_s[jr * 72 + c0]     = *(const bf16x8*)gk;
            *(bf16x8*)&sh.k_s[jr * 72 + c0 + 8] = *(const bf16x8*)(gk + 8);
            const u16* gv = vT + (size_t)(bh * DH + jr) * krows + koff + jt * 64 + c0;
            *(bf16x8*)&sh.v_s[jr * 72 + c0]     = *(const bf16x8*)gv;
            *(bf16x8*)&sh.v_s[jr * 72 + c0 + 8] = *(const bf16x8*)(gv + 8);
        }
        __syncthreads();
#pragma unroll
        for (int u = 0; u < 2; ++u) {
            int j0 = nb + u * 16;
            f32x4 d = {};
#pragma unroll
            for (int kk = 0; kk < 2; ++kk) {
                bf16x8 aq = *(bf16x8*)&sh.q_s[(i0 + fr) * 72 + kk * 32 + fg * 8];
                bf16x8 bk = *(bf16x8*)&sh.k_s[(j0 + fr) * 72 + kk * 32 + fg * 8];
                d = __builtin_amdgcn_mfma_f32_16x16x32_bf16(aq, bk, d, 0, 0, 0);
            }
#pragma unroll
            for (int r = 0; r < 4; ++r)
                sh.s_s[(i0 + fg * 4 + r) * 65 + j0 + fr] = d[r] * ATT_SCALE;
        }
        __syncthreads();
        {
            float v[8];
#pragma unroll
            for (int u = 0; u < 8; ++u) v[u] = sh.s_s[srow * 65 + sc0 + u];
            float tmax = v[0];
#pragma unroll
            for (int u = 1; u < 8; ++u) tmax = fmaxf(tmax, v[u]);
            tmax = fmaxf(tmax, __shfl_xor(tmax, 1));
            tmax = fmaxf(tmax, __shfl_xor(tmax, 2));
            tmax = fmaxf(tmax, __shfl_xor(tmax, 4));
            float m_new = fmaxf(m_run, tmax);
            float scl = __expf(m_run - m_new);
            float psum = 0.f;
            union { u16 us[8]; bf16x8 v8; } pk;
#pragma unroll
            for (int u = 0; u < 8; ++u) {
                float p = __expf(v[u] - m_new);
                psum += p;
                pk.us[u] = f2b(p);
            }
            psum += __shfl_xor(psum, 1);
            psum += __shfl_xor(psum, 2);
            psum += __shfl_xor(psum, 4);
            l_run = l_run * scl + psum;
            m_run = m_new;
            *(bf16x8*)&sh.p_s[srow * 72 + sc0] = pk.v8;
            if ((tid & 7) == 0) sh.scale_s[srow] = scl;
        }
        __syncthreads();
#pragma unroll
        for (int u = 0; u < 2; ++u)
#pragma unroll
            for (int r = 0; r < 4; ++r) oacc[u][r] *= sh.scale_s[i0 + fg * 4 + r];
#pragma unroll
        for (int u = 0; u < 2; ++u) {
            int n0 = nb + u * 16;
#pragma unroll
            for (int kk = 0; kk < 2; ++kk) {
                bf16x8 ap = *(bf16x8*)&sh.p_s[(i0 + fr) * 72 + kk * 32 + fg * 8];
                bf16x8 bv = *(bf16x8*)&sh.v_s[(n0 + fr) * 72 + kk * 32 + fg * 8];
                oacc[u] = __builtin_amdgcn_mfma_f32_16x16x32_bf16(ap, bv, oacc[u], 0, 0, 0);
            }
        }
    }
    if ((tid & 7) == 0) sh.l_s[srow] = l_run;
    __syncthreads();
#pragma unroll
    for (int u = 0; u < 2; ++u)
#pragma unroll
        for (int r = 0; r < 4; ++r)
            out[u][r] = oacc[u][r] / sh.l_s[i0 + fg * 4 + r];
}

// ---------------- main causal attention
__global__ __launch_bounds__(256)
void attn_main(const u16* __restrict__ q_bf, const u16* __restrict__ kmat,
               const u16* __restrict__ vT, u16* __restrict__ out_bf) {
    const int it = blockIdx.x, bh = blockIdx.y;
    const int b = bh >> 3, h = bh & 7;
    const int ib = it * 32;
    const int tid = threadIdx.x;
    const int lane = tid & 63, wave = tid >> 6;
    __shared__ AttnShared sh;

    {
        int r = tid >> 3, c0 = (tid & 7) * 8;
        *(bf16x8*)&sh.q_s[r * 72 + c0] =
            *(const bf16x8*)&q_bf[(size_t)(b * TLEN + ib + r) * DMODEL + h * DH + c0];
    }

    const int srow = tid >> 3, sc0 = (tid & 7) * 8;
    float m_run = -1e30f, l_run = 0.f;
    const int i0 = (wave >> 1) * 16;
    const int nb = (wave & 1) * 32;
    const int fr = lane & 15, fg = lane >> 4;
    f32x4 oacc[2] = {};
    int njt = ((ib + 671) >> 6) + 1;

    for (int jt = 0; jt < njt; ++jt) {
        __syncthreads();
        {
            int jr = tid >> 2, c0 = (tid & 3) * 16;
            const u16* gk = kmat + (size_t)(b * KVLEN + jt * 64 + jr) * 1024 + h * DH + c0;
            *(bf16x8*)&sh.k_s[jr * 72 + c0]     = *(const bf16x8*)gk;
            *(bf16x8*)&sh.k_s[jr * 72 + c0 + 8] = *(const bf16x8*)(gk + 8);
            const u16* gv = vT + (size_t)(bh * DH + jr) * KVLEN + jt * 64 + c0;
            *(bf16x8*)&sh.v_s[jr * 72 + c0]     = *(const bf16x8*)gv;
            *(bf16x8*)&sh.v_s[jr * 72 + c0 + 8] = *(const bf16x8*)(gv + 8);
        }
        __syncthreads();
#pragma unroll
        for (int u = 0; u < 2; ++u) {
            int j0 = nb + u * 16;
            f32x4 d = {};
#pragma unroll
            for (int kk = 0; kk < 2; ++kk) {
                bf16x8 aq = *(bf16x8*)&sh.q_s[(i0 + fr) * 72 + kk * 32 + fg * 8];
                bf16x8 bk = *(bf16x8*)&sh.k_s[(j0 + fr) * 72 + kk * 32 + fg * 8];
                d = __builtin_amdgcn_mfma_f32_16x16x32_bf16(aq, bk, d, 0, 0, 0);
            }
#pragma unroll
            for (int r = 0; r < 4; ++r) {
                int irow = i0 + fg * 4 + r;
                int jcol = j0 + fr;
                float sv = d[r] * ATT_SCALE;
                int jg = jt * 64 + jcol;
                int ig = ib + irow;
                if (jg > ig + TOTALMEM) sv = -1e30f;
                sh.s_s[irow * 65 + jcol] = sv;
            }
        }
        __syncthreads();
        {
            float v[8];
#pragma unroll
            for (int u = 0; u < 8; ++u) v[u] = sh.s_s[srow * 65 + sc0 + u];
            float tmax = v[0];
#pragma unroll
            for (int u = 1; u < 8; ++u) tmax = fmaxf(tmax, v[u]);
            tmax = fmaxf(tmax, __shfl_xor(tmax, 1));
            tmax = fmaxf(tmax, __shfl_xor(tmax, 2));
            tmax = fmaxf(tmax, __shfl_xor(tmax, 4));
            float m_new = fmaxf(m_run, tmax);
            float scl = __expf(m_run - m_new);
            float psum = 0.f;
            union { u16 us[8]; bf16x8 v8; } pk;
#pragma unroll
            for (int u = 0; u < 8; ++u) {
                float p = __expf(v[u] - m_new);
                psum += p;
                pk.us[u] = f2b(p);
            }
            psum += __shfl_xor(psum, 1);
            psum += __shfl_xor(psum, 2);
            psum += __shfl_xor(psum, 4);
            l_run = l_run * scl + psum;
            m_run = m_new;
            *(bf16x8*)&sh.p_s[srow * 72 + sc0] = pk.v8;
            if ((tid & 7) == 0) sh.scale_s[srow] = scl;
        }
        __syncthreads();
#pragma unroll
        for (int u = 0; u < 2; ++u)
#pragma unroll
            for (int r = 0; r < 4; ++r) oacc[u][r] *= sh.scale_s[i0 + fg * 4 + r];
#pragma unroll
        for (int u = 0; u < 2; ++u) {
            int n0 = nb + u * 16;
#pragma unroll
            for (int kk = 0; kk < 2; ++kk) {
                bf16x8 ap = *(bf16x8*)&sh.p_s[(i0 + fr) * 72 + kk * 32 + fg * 8];
                bf16x8 bv = *(bf16x8*)&sh.v_s[(n0 + fr) * 72 + kk * 32 + fg * 8];
                oacc[u] = __builtin_amdgcn_mfma_f32_16x16x32_bf16(ap, bv, oacc[u], 0, 0, 0);
            }
        }
    }

    if ((tid & 7) == 0) sh.l_s[srow] = l_run;
    __syncthreads();
#pragma unroll
    for (int u = 0; u < 2; ++u) {
        int n0 = nb + u * 16;
#pragma unroll
        for (int r = 0; r < 4; ++r) {
            int irow = i0 + fg * 4 + r;
            float val = oacc[u][r] / sh.l_s[irow];
            out_bf[(size_t)(b * TLEN + ib + irow) * DMODEL + h * DH + n0 + fr] = f2b(val);
        }
    }
}

// ---------------- fused aux loss attention (mem-attn and cmem-attn, diff in-register)
__global__ __launch_bounds__(256)
void attn_aux(const u16* __restrict__ q_bf,
              const u16* __restrict__ kmat_m, const u16* __restrict__ vT_m,
              const u16* __restrict__ kmat_c, const u16* __restrict__ vT_c,
              float* __restrict__ acc_sum) {
    const int it = blockIdx.x, bh = blockIdx.y;
    const int b = bh >> 3, h = bh & 7;
    const int ib = it * 32;
    const int tid = threadIdx.x;
    const int lane = tid & 63, wave = tid >> 6;
    __shared__ AttnShared sh;

    {
        int r = tid >> 3, c0 = (tid & 7) * 8;
        *(bf16x8*)&sh.q_s[r * 72 + c0] =
            *(const bf16x8*)&q_bf[(size_t)(b * TLEN + ib + r) * DMODEL + h * DH + c0];
    }

    f32x4 o1[2], o2[2];
    attn_nc_phase(sh, kmat_m, vT_m, KVLEN, 128, 8, b, bh, h, tid, o1);
    attn_nc_phase(sh, kmat_c, vT_c, 128, 0, 2, b, bh, h, tid, o2);

    float lsum = 0.f;
#pragma unroll
    for (int u = 0; u < 2; ++u)
#pragma unroll
        for (int r = 0; r < 4; ++r) {
            float d = o1[u][r] - o2[u][r];
            lsum += d * d;
        }
    lsum = wave_red_sum(lsum);
    if (lane == 0) sh.red_s[wave] = lsum;
    __syncthreads();
    if (tid == 0) atomicAdd(acc_sum, sh.red_s[0] + sh.red_s[1] + sh.red_s[2] + sh.red_s[3]);
}

// ---------------- ae loss
__global__ __launch_bounds__(256)
void ae_loss_kernel(const float* __restrict__ cmem_new,
                    const float* __restrict__ mem,
                    const float* __restrict__ dw,
                    const float* __restrict__ db,
                    float* __restrict__ acc) {
    int b = blockIdx.x >> 7;
    int m0 = (blockIdx.x & 127) * 4;
    __shared__ float w_s[4][128];
    __shared__ float red_s2[4];
    int tid = threadIdx.x;
    if (tid < 128) {
#pragma unroll
        for (int mm = 0; mm < 4; ++mm) w_s[mm][tid] = dw[(m0 + mm) * 128 + tid];
    }
    __syncthreads();
    float lsum = 0.f;
#pragma unroll
    for (int rep = 0; rep < 2; ++rep) {
        int dd = tid + rep * 256;
        float a0 = 0, a1 = 0, a2 = 0, a3 = 0;
        for (int c = 0; c < 128; ++c) {
            float cv = cmem_new[(size_t)b * 65536 + c * 512 + dd];
            a0 += cv * w_s[0][c]; a1 += cv * w_s[1][c];
            a2 += cv * w_s[2][c]; a3 += cv * w_s[3][c];
        }
#pragma unroll
        for (int mm = 0; mm < 4; ++mm) {
            float a = (mm == 0) ? a0 : (mm == 1) ? a1 : (mm == 2) ? a2 : a3;
            float d = mem[(size_t)(b * 512 + m0 + mm) * 512 + dd] - (a + db[m0 + mm]);
            lsum += d * d;
        }
    }
    lsum = wave_red_sum(lsum);
    if ((tid & 63) == 0) red_s2[tid >> 6] = lsum;
    __syncthreads();
    if (tid == 0) atomicAdd(acc, red_s2[0] + red_s2[1] + red_s2[2] + red_s2[3]);
}

__global__ void finalize(const float* __restrict__ acc, float* __restrict__ out) {
    if (threadIdx.x == 0) {
        out[0] = acc[0] * (1.f / 2097152.f);
        out[1] = acc[1] * (1.f / 2097152.f);
    }
}

// ---------------- launch ----------------
extern "C" void kernel_launch(void* const* d_in, const int* in_sizes, int n_in,
                              void* d_out, int out_size, void* d_ws, size_t ws_size,
                              hipStream_t stream) {
    const float* x      = (const float*)d_in[0];
    const float* mem    = (const float*)d_in[1];
    const float* cmem   = (const float*)d_in[2];
    const float* Wq     = (const float*)d_in[3];
    const float* Wkv    = (const float*)d_in[4];
    const float* Wo     = (const float*)d_in[5];
    const float* bo     = (const float*)d_in[6];
    const float* conv_w = (const float*)d_in[7];
    const float* conv_b = (const float*)d_in[8];
    const float* deconv_w = (const float*)d_in[9];
    const float* deconv_b = (const float*)d_in[10];
    float* out = (float*)d_out;

    char* w = (char*)d_ws;
    auto alloc = [&](size_t bytes) { char* p = w; w += (bytes + 255) & ~255ull; return p; };
    u16* Wq_bf   = (u16*)alloc(262144 * 2);
    u16* Wkv_bf  = (u16*)alloc(524288 * 2);
    u16* Wo_bf   = (u16*)alloc(262144 * 2);
    u16* cw2_bf  = (u16*)alloc(1048576 * 2);
    u16* kvin_bf = (u16*)alloc(4718592 * 2);
    u16* q_bf    = (u16*)alloc(2097152 * 2);
    u16* kv_bf   = (u16*)alloc(9437184 * 2);
    u16* comp_bf = (u16*)alloc(524288 * 2);
    u16* ckv_bf  = (u16*)alloc(1048576 * 2);
    u16* vTm     = (u16*)alloc(4718592 * 2);
    u16* vTc     = (u16*)alloc(524288 * 2);
    u16* attn_bf = (u16*)alloc(2097152 * 2);
    float* part  = (float*)alloc(8 * 524288 * 4);
    float* accs  = (float*)alloc(256);

    float* logits_o  = out;
    float* newmem_o  = out + 2097152;
    float* newcmem_o = out + 4194304;
    float* scalars_o = out + 4718592;

    prep_kernel<<<6656, 256, 0, stream>>>(x, mem, cmem, Wq, Wkv, Wo, conv_w,
                                          kvin_bf, Wq_bf, Wkv_bf, Wo_bf, cw2_bf, accs);
    hipMemcpyAsync(newmem_o, x, 2097152 * sizeof(float), hipMemcpyDeviceToDevice, stream);

    // q projection: A = kvin x-slice
    gemm_bt<<<dim3(32, 4), 256, 0, stream>>>(kvin_bf + 327680, 512, 512, 589824,
                                             Wq_bf, 512, 512,
                                             nullptr, 0, nullptr, q_bf, 512, nullptr);
    // kv projection: A = kvin full
    gemm_bt<<<dim3(72, 8), 256, 0, stream>>>(kvin_bf, 512, 9216, 0,
                                             Wkv_bf, 512, 512,
                                             nullptr, 0, nullptr, kv_bf, 1024, nullptr);
    transpose_v<<<dim3(18, 64), 256, 0, stream>>>(kv_bf, vTm, KVLEN);

    // conv compression as split-K GEMM over kvin mem-slice
    gemm_bt<<<dim3(8, 4, 8), 256, 0, stream>>>(kvin_bf + 65536, 2048, 128, 589824,
                                               cw2_bf, 2048, 256,
                                               part, 524288, nullptr, nullptr, 512, nullptr);
    conv_reduce<<<512, 256, 0, stream>>>(part, conv_b, newcmem_o, comp_bf);

    gemm_bt<<<dim3(8, 8), 256, 0, stream>>>(comp_bf, 512, 1024, 0,
                                            Wkv_bf, 512, 512,
                                            nullptr, 0, nullptr, ckv_bf, 1024, nullptr);
    transpose_v<<<dim3(2, 64), 256, 0, stream>>>(ckv_bf, vTc, 128);

    // main attention + output projection
    attn_main<<<dim3(16, 64), 256, 0, stream>>>(q_bf, kv_bf, vTm, attn_bf);
    gemm_bt<<<dim3(32, 4), 256, 0, stream>>>(attn_bf, 512, 4096, 0,
                                             Wo_bf, 512, 512,
                                             nullptr, 0, logits_o, nullptr, 512, bo);

    // aux + ae losses
    attn_aux<<<dim3(16, 64), 256, 0, stream>>>(q_bf, kv_bf, vTm, ckv_bf, vTc, accs);
    ae_loss_kernel<<<1024, 256, 0, stream>>>(newcmem_o, mem, deconv_w, deconv_b, accs + 1);
    finalize<<<1, 64, 0, stream>>>(accs, scalars_o);
}

// Round 3
// 197.490 us; speedup vs baseline: 1.5458x; 1.4848x over previous
//
#include <hip/hip_runtime.h>

typedef __bf16 bf16x8 __attribute__((ext_vector_type(8)));
typedef float f32x4 __attribute__((ext_vector_type(4)));
typedef float f32x16 __attribute__((ext_vector_type(16)));
typedef unsigned short u16;
typedef unsigned int u32;

#define TLEN 512
#define DMODEL 512
#define DH 64
#define KVLEN 1152
#define TOTALMEM 640

__device__ inline u16 f2b(float f) {
    union { float f; u32 u; } x; x.f = f;
    u32 u = x.u;
    return (u16)((u + 0x7FFFu + ((u >> 16) & 1u)) >> 16);
}

__device__ inline float wave_red_sum(float v) {
#pragma unroll
    for (int off = 1; off < 64; off <<= 1) v += __shfl_xor(v, off);
    return v;
}

__device__ inline void gload16(const u16* g, u16* l) {
    __builtin_amdgcn_global_load_lds((const __attribute__((address_space(1))) void*)g,
                                     (__attribute__((address_space(3))) void*)l, 16, 0, 0);
}

__device__ __forceinline__ u32 cvtpk_bf16(float lo, float hi) {
    u32 r;
    asm("v_cvt_pk_bf16_f32 %0, %1, %2" : "=v"(r) : "v"(lo), "v"(hi));
    return r;
}

// ---------------- fused prep (unchanged from r2)
__global__ __launch_bounds__(256)
void prep_kernel(const float* __restrict__ x, const float* __restrict__ mem,
                 const float* __restrict__ cmem, const float* __restrict__ Wq,
                 const float* __restrict__ Wkv, const float* __restrict__ Wo,
                 const float* __restrict__ cw,
                 u16* __restrict__ kvin, u16* __restrict__ wq_b, u16* __restrict__ wkv_b,
                 u16* __restrict__ wo_b, u16* __restrict__ cw2, float* __restrict__ accs) {
    int idx = blockIdx.x * 256 + threadIdx.x;
    if (idx == 0) { accs[0] = 0.f; accs[1] = 0.f; }
    int e = idx * 4;
    float4 v;
    u16* o;
    if (e < 4718592) {
        int row = e >> 9, col = e & 511;
        int b = row / KVLEN, p = row - b * KVLEN;
        const float* src;
        if (p < 128)       src = cmem + ((size_t)(b * 128 + p)) * 512 + col;
        else if (p < 640)  src = mem  + ((size_t)(b * 512 + (p - 128))) * 512 + col;
        else               src = x    + ((size_t)(b * 512 + (p - 640))) * 512 + col;
        v = *(const float4*)src; o = kvin + e;
    } else if (e < 4980736) {
        int t = e - 4718592; v = *(const float4*)(Wq + t); o = wq_b + t;
    } else if (e < 5505024) {
        int t = e - 4980736; v = *(const float4*)(Wkv + t); o = wkv_b + t;
    } else if (e < 5767168) {
        int t = e - 5505024; v = *(const float4*)(Wo + t); o = wo_b + t;
    } else {
        int t = e - 5767168;
        int oo = t >> 11, rem = t & 2047, tt = rem >> 9, ii = rem & 511;
        const float* s0 = cw + oo * 2048 + tt;
        v.x = s0[(ii + 0) * 4]; v.y = s0[(ii + 1) * 4];
        v.z = s0[(ii + 2) * 4]; v.w = s0[(ii + 3) * 4];
        o = cw2 + t;
    }
    o[0] = f2b(v.x); o[1] = f2b(v.y); o[2] = f2b(v.z); o[3] = f2b(v.w);
}

// ---------------- generic bf16 MFMA GEMM (m97 staging) — unchanged from r2
__global__ __launch_bounds__(256)
void gemm_bt(const u16* __restrict__ A, int lda, int rowsPerB, long long bstride,
             const u16* __restrict__ Bt, int ldb, int Kb,
             float* __restrict__ Cpart, int partStride,
             float* __restrict__ Cf, u16* __restrict__ Cb, int ldc,
             const float* __restrict__ bias) {
    __shared__ u16 As[128 * 32];
    __shared__ u16 Bs[128 * 32];
    const int tid = threadIdx.x;
    const int lane = tid & 63, wave = tid >> 6;
    const int wr = (wave >> 1) * 64, wc = (wave & 1) * 64;
    const int fr = lane & 15, fg = lane >> 4;
    const int arow0 = blockIdx.x * 128;
    const int brow0 = blockIdx.y * 128;
    const int k0start = blockIdx.z * Kb;

    const int lrow = lane >> 2;
    const int lcol = (lane & 3) * 8;
    const u16* gA[2]; const u16* gB[2];
#pragma unroll
    for (int i = 0; i < 2; ++i) {
        int r = wave * 32 + i * 16 + lrow;
        int gr = arow0 + r;
        int bb = gr / rowsPerB;
        int lr = gr - bb * rowsPerB;
        gA[i] = A + (size_t)bb * bstride + (size_t)lr * lda + k0start + lcol;
        gB[i] = Bt + (size_t)(brow0 + r) * ldb + k0start + lcol;
    }
    u16* lA0 = &As[(wave * 32) * 32];
    u16* lA1 = &As[(wave * 32 + 16) * 32];
    u16* lB0 = &Bs[(wave * 32) * 32];
    u16* lB1 = &Bs[(wave * 32 + 16) * 32];

    f32x4 acc[4][4] = {};
    for (int k = 0; k < Kb; k += 32) {
        __syncthreads();
        gload16(gA[0] + k, lA0);
        gload16(gA[1] + k, lA1);
        gload16(gB[0] + k, lB0);
        gload16(gB[1] + k, lB1);
        __syncthreads();
        bf16x8 af[4], bfr[4];
#pragma unroll
        for (int m = 0; m < 4; ++m) af[m] = *(bf16x8*)&As[(wr + m * 16 + fr) * 32 + fg * 8];
#pragma unroll
        for (int n = 0; n < 4; ++n) bfr[n] = *(bf16x8*)&Bs[(wc + n * 16 + fr) * 32 + fg * 8];
#pragma unroll
        for (int m = 0; m < 4; ++m)
#pragma unroll
            for (int n = 0; n < 4; ++n)
                acc[m][n] = __builtin_amdgcn_mfma_f32_16x16x32_bf16(af[m], bfr[n], acc[m][n], 0, 0, 0);
    }

#pragma unroll
    for (int m = 0; m < 4; ++m)
#pragma unroll
        for (int n = 0; n < 4; ++n)
#pragma unroll
            for (int r = 0; r < 4; ++r) {
                int row = arow0 + wr + m * 16 + fg * 4 + r;
                int col = brow0 + wc + n * 16 + fr;
                float v = acc[m][n][r];
                if (Cpart) {
                    Cpart[(size_t)blockIdx.z * partStride + (size_t)row * ldc + col] = v;
                } else {
                    if (bias) v += bias[col];
                    if (Cf) Cf[(size_t)row * ldc + col] = v;
                    if (Cb) Cb[(size_t)row * ldc + col] = f2b(v);
                }
            }
}

// ---------------- split-K reduce for conv (unchanged)
__global__ __launch_bounds__(256)
void conv_reduce(const float* __restrict__ part, const float* __restrict__ cb,
                 float* __restrict__ outf, u16* __restrict__ outb) {
    int idx = (blockIdx.x * 256 + threadIdx.x) * 4;
    float4 s = *(const float4*)(part + idx);
#pragma unroll
    for (int sp = 1; sp < 8; ++sp) {
        float4 p = *(const float4*)(part + (size_t)sp * 524288 + idx);
        s.x += p.x; s.y += p.y; s.z += p.z; s.w += p.w;
    }
    float4 bb = *(const float4*)(cb + (idx & 511));
    s.x += bb.x; s.y += bb.y; s.z += bb.z; s.w += bb.w;
    *(float4*)(outf + idx) = s;
    outb[idx + 0] = f2b(s.x); outb[idx + 1] = f2b(s.y);
    outb[idx + 2] = f2b(s.z); outb[idx + 3] = f2b(s.w);
}

// ---------------- V transpose (unchanged)
__global__ __launch_bounds__(256)
void transpose_v(const u16* __restrict__ kv, u16* __restrict__ vT, int rowsPerB) {
    int jt = blockIdx.x, bh = blockIdx.y;
    int b = bh >> 3, h = bh & 7;
    __shared__ u16 t_s[64 * 65];
    int tid = threadIdx.x;
    int jr = tid >> 2, c0 = (tid & 3) * 16;
    const u16* g = kv + (size_t)(b * rowsPerB + jt * 64 + jr) * 1024 + 512 + h * DH + c0;
#pragma unroll
    for (int u = 0; u < 16; ++u) t_s[jr * 65 + c0 + u] = g[u];
    __syncthreads();
    int dh = tid >> 2, j0 = (tid & 3) * 16;
    union { u16 us[8]; bf16x8 v8; } o1, o2;
#pragma unroll
    for (int u = 0; u < 8; ++u) {
        o1.us[u] = t_s[(j0 + u) * 65 + dh];
        o2.us[u] = t_s[(j0 + 8 + u) * 65 + dh];
    }
    u16* o = vT + (size_t)(bh * DH + dh) * rowsPerB + jt * 64 + j0;
    *(bf16x8*)o = o1.v8;
    *(bf16x8*)(o + 8) = o2.v8;
}

// ================= NEW attention: swapped-QK, in-register softmax =================
// Per warp: 32 q rows. S^T = mfma32x32x16(K, Q^T): lane holds S[j=(r&3)+8*(r>>2)+4*hi][i=lane&31].
// P->bf16 A-frags via cvt_pk_bf16 + permlane32_swap (VDST.hi <-> SRC.lo).
// K tile [64j][64d] and V^T tile [64dh][64j] in XOR-swizzled LDS (slot ^= row&7), double-buffered.
template <bool MASK>
__device__ __forceinline__ void attn_pass(
    const u16* __restrict__ kbase, int kstride,
    const u16* __restrict__ vbase, int vstride,
    int njt, int tid, int iq_min,
    const bf16x8* qf, u16* k_s, u16* v_s,
    f32x16& o0, f32x16& o1, float& m_run, float& l_run)
{
    const int lane = tid & 63;
    const int c31 = lane & 31;
    const int hi = lane >> 5;
    const int hi4 = hi << 2;
    const int srow = tid >> 2, ssl = tid & 3;
    const int kwa = srow * 64 + ((ssl ^ (srow & 7)) << 3);
    const int kwb = srow * 64 + (((ssl + 4) ^ (srow & 7)) << 3);
    const int iq = iq_min + c31;

    int krd[2][4];
#pragma unroll
    for (int jsub = 0; jsub < 2; ++jsub) {
        int row = jsub * 32 + c31;
#pragma unroll
        for (int ks = 0; ks < 4; ++ks)
            krd[jsub][ks] = row * 64 + (((2 * ks + hi) ^ (row & 7)) << 3);
    }
    int vrd[2][4];
#pragma unroll
    for (int half = 0; half < 2; ++half) {
        int row = half * 32 + c31;
#pragma unroll
        for (int s = 0; s < 4; ++s)   // s = jsub*2 + ksub
            vrd[half][s] = row * 64 + (((2 * s + hi) ^ (row & 7)) << 3);
    }

    float4 lk0, lk1, lv0, lv1;
#define AT_LOAD(T) { \
        const u16* gk = kbase + (size_t)((T) * 64 + srow) * kstride + ssl * 8; \
        lk0 = *(const float4*)gk; lk1 = *(const float4*)(gk + 32); \
        const u16* gv = vbase + (size_t)srow * vstride + (T) * 64 + ssl * 8; \
        lv0 = *(const float4*)gv; lv1 = *(const float4*)(gv + 32); }
#define AT_STORE(B) { \
        u16* kd = k_s + (B) * 4096; u16* vd = v_s + (B) * 4096; \
        *(float4*)(kd + kwa) = lk0; *(float4*)(kd + kwb) = lk1; \
        *(float4*)(vd + kwa) = lv0; *(float4*)(vd + kwb) = lv1; }

    AT_LOAD(0); AT_STORE(0);
    __syncthreads();

    for (int t = 0; t < njt; ++t) {
        const int cur = t & 1;
        if (t + 1 < njt) AT_LOAD(t + 1);
        const u16* ks_ = k_s + cur * 4096;
        const u16* vs_ = v_s + cur * 4096;

        f32x16 sA = {}, sB = {};
#pragma unroll
        for (int ks = 0; ks < 4; ++ks) {
            bf16x8 a0 = *(const bf16x8*)&ks_[krd[0][ks]];
            sA = __builtin_amdgcn_mfma_f32_32x32x16_bf16(a0, qf[ks], sA, 0, 0, 0);
        }
#pragma unroll
        for (int ks = 0; ks < 4; ++ks) {
            bf16x8 a1 = *(const bf16x8*)&ks_[krd[1][ks]];
            sB = __builtin_amdgcn_mfma_f32_32x32x16_bf16(a1, qf[ks], sB, 0, 0, 0);
        }
        if (MASK) {
            if (t * 64 + 63 > iq_min + TOTALMEM) {
#pragma unroll
                for (int r = 0; r < 16; ++r) {
                    int rj = (r & 3) + 8 * (r >> 2) + hi4;
                    if (t * 64 + rj > iq + TOTALMEM) sA[r] = -1e30f;
                    if (t * 64 + 32 + rj > iq + TOTALMEM) sB[r] = -1e30f;
                }
            }
        }
        float tmax = sA[0];
#pragma unroll
        for (int r = 1; r < 16; ++r) tmax = fmaxf(tmax, sA[r]);
#pragma unroll
        for (int r = 0; r < 16; ++r) tmax = fmaxf(tmax, sB[r]);
        tmax = fmaxf(tmax, __shfl_xor(tmax, 32));
        tmax *= 0.125f;
        if (__any(tmax > m_run + 8.0f)) {          // defer-max (T13)
            float m_new = fmaxf(m_run, tmax);
            float scl = __expf(m_run - m_new);
            m_run = m_new;
            l_run *= scl;
#pragma unroll
            for (int r = 0; r < 16; ++r) {
                float sc = __shfl(scl, (r & 3) + 8 * (r >> 2) + hi4);
                o0[r] *= sc; o1[r] *= sc;
            }
        }
        const float negm = -m_run;
        float ps = 0.f;
#pragma unroll
        for (int jsub = 0; jsub < 2; ++jsub) {
#pragma unroll
            for (int ksub = 0; ksub < 2; ++ksub) {
                float p0 = __expf(fmaf((jsub ? sB[ksub * 8 + 0] : sA[ksub * 8 + 0]), 0.125f, negm));
                float p1 = __expf(fmaf((jsub ? sB[ksub * 8 + 1] : sA[ksub * 8 + 1]), 0.125f, negm));
                float p2 = __expf(fmaf((jsub ? sB[ksub * 8 + 2] : sA[ksub * 8 + 2]), 0.125f, negm));
                float p3 = __expf(fmaf((jsub ? sB[ksub * 8 + 3] : sA[ksub * 8 + 3]), 0.125f, negm));
                float p4 = __expf(fmaf((jsub ? sB[ksub * 8 + 4] : sA[ksub * 8 + 4]), 0.125f, negm));
                float p5 = __expf(fmaf((jsub ? sB[ksub * 8 + 5] : sA[ksub * 8 + 5]), 0.125f, negm));
                float p6 = __expf(fmaf((jsub ? sB[ksub * 8 + 6] : sA[ksub * 8 + 6]), 0.125f, negm));
                float p7 = __expf(fmaf((jsub ? sB[ksub * 8 + 7] : sA[ksub * 8 + 7]), 0.125f, negm));
                ps += ((p0 + p1) + (p2 + p3)) + ((p4 + p5) + (p6 + p7));
                u32 X = cvtpk_bf16(p0, p1);
                u32 Z = cvtpk_bf16(p2, p3);
                u32 Y = cvtpk_bf16(p4, p5);
                u32 W = cvtpk_bf16(p6, p7);
                auto s1 = __builtin_amdgcn_permlane32_swap(X, Y, false, false);
                auto s2 = __builtin_amdgcn_permlane32_swap(Z, W, false, false);
                union { u32 w[4]; bf16x8 v; } fa;
                fa.w[0] = (u32)s1[0]; fa.w[1] = (u32)s2[0];
                fa.w[2] = (u32)s1[1]; fa.w[3] = (u32)s2[1];
                bf16x8 bv0 = *(const bf16x8*)&vs_[vrd[0][jsub * 2 + ksub]];
                bf16x8 bv1 = *(const bf16x8*)&vs_[vrd[1][jsub * 2 + ksub]];
                o0 = __builtin_amdgcn_mfma_f32_32x32x16_bf16(fa.v, bv0, o0, 0, 0, 0);
                o1 = __builtin_amdgcn_mfma_f32_32x32x16_bf16(fa.v, bv1, o1, 0, 0, 0);
            }
        }
        ps += __shfl_xor(ps, 32);
        l_run += ps;
        if (t + 1 < njt) AT_STORE(cur ^ 1);
        __syncthreads();
    }
#undef AT_LOAD
#undef AT_STORE
}

__global__ __launch_bounds__(256)
void attn_main2(const u16* __restrict__ q_bf, const u16* __restrict__ kv,
                const u16* __restrict__ vT, u16* __restrict__ out_bf) {
    __shared__ u16 k_s[2 * 4096];
    __shared__ u16 v_s[2 * 4096];
    const int it = blockIdx.x, bh = blockIdx.y;
    const int b = bh >> 3, h = bh & 7;
    const int tid = threadIdx.x;
    const int w = tid >> 6, lane = tid & 63;
    const int c31 = lane & 31, hi4 = (lane >> 5) << 2;
    const int iwmin = it * 128 + w * 32;
    const int iq = iwmin + c31;

    bf16x8 qf[4];
#pragma unroll
    for (int ks = 0; ks < 4; ++ks)
        qf[ks] = *(const bf16x8*)&q_bf[(size_t)(b * TLEN + iq) * DMODEL + h * DH + ks * 16 + hi4 * 2];

    const u16* kbase = kv + (size_t)b * KVLEN * 1024 + h * DH;
    const u16* vbase = vT + (size_t)(bh * DH) * KVLEN;
    const int njt = ((it * 128 + 767) >> 6) + 1;

    f32x16 o0 = {}, o1 = {};
    float m_run = -1e30f, l_run = 0.f;
    attn_pass<true>(kbase, 1024, vbase, KVLEN, njt, tid, iwmin, qf, k_s, v_s, o0, o1, m_run, l_run);

    float linv = 1.0f / l_run;
#pragma unroll
    for (int r = 0; r < 16; ++r) {
        int R = (r & 3) + 8 * (r >> 2) + hi4;
        float li = __shfl(linv, R);
        int i = iwmin + R;
        u16* o = out_bf + (size_t)(b * TLEN + i) * DMODEL + h * DH + c31;
        o[0]  = f2b(o0[r] * li);
        o[32] = f2b(o1[r] * li);
    }
}

__global__ __launch_bounds__(256)
void attn_aux2(const u16* __restrict__ q_bf, const u16* __restrict__ kv,
               const u16* __restrict__ vTm_, const u16* __restrict__ ckv,
               const u16* __restrict__ vTc_, float* __restrict__ acc_sum) {
    __shared__ u16 k_s[2 * 4096];
    __shared__ u16 v_s[2 * 4096];
    __shared__ float red_s[4];
    const int it = blockIdx.x, bh = blockIdx.y;
    const int b = bh >> 3, h = bh & 7;
    const int tid = threadIdx.x;
    const int w = tid >> 6, lane = tid & 63;
    const int c31 = lane & 31, hi4 = (lane >> 5) << 2;
    const int iwmin = it * 128 + w * 32;
    const int iq = iwmin + c31;

    bf16x8 qf[4];
#pragma unroll
    for (int ks = 0; ks < 4; ++ks)
        qf[ks] = *(const bf16x8*)&q_bf[(size_t)(b * TLEN + iq) * DMODEL + h * DH + ks * 16 + hi4 * 2];

    f32x16 o0 = {}, o1 = {};
    float m_run = -1e30f, l_run = 0.f;
    attn_pass<false>(kv + (size_t)(b * KVLEN + 128) * 1024 + h * DH, 1024,
                     vTm_ + (size_t)(bh * DH) * KVLEN + 128, KVLEN, 8,
                     tid, 0, qf, k_s, v_s, o0, o1, m_run, l_run);
    float n0[16], n1[16];
    {
        float linv = 1.0f / l_run;
#pragma unroll
        for (int r = 0; r < 16; ++r) {
            float li = __shfl(linv, (r & 3) + 8 * (r >> 2) + hi4);
            n0[r] = o0[r] * li;
            n1[r] = o1[r] * li;
        }
    }
    f32x16 c0 = {}, c1 = {};
    m_run = -1e30f; l_run = 0.f;
    attn_pass<false>(ckv + (size_t)(b * 128) * 1024 + h * DH, 1024,
                     vTc_ + (size_t)(bh * DH) * 128, 128, 2,
                     tid, 0, qf, k_s, v_s, c0, c1, m_run, l_run);
    float lsum = 0.f;
    {
        float linv = 1.0f / l_run;
#pragma unroll
        for (int r = 0; r < 16; ++r) {
            float li = __shfl(linv, (r & 3) + 8 * (r >> 2) + hi4);
            float d0 = n0[r] - c0[r] * li;
            float d1 = n1[r] - c1[r] * li;
            lsum += d0 * d0 + d1 * d1;
        }
    }
    lsum = wave_red_sum(lsum);
    if (lane == 0) red_s[w] = lsum;
    __syncthreads();
    if (tid == 0) atomicAdd(acc_sum, red_s[0] + red_s[1] + red_s[2] + red_s[3]);
}

// ---------------- ae loss (unchanged)
__global__ __launch_bounds__(256)
void ae_loss_kernel(const float* __restrict__ cmem_new,
                    const float* __restrict__ mem,
                    const float* __restrict__ dw,
                    const float* __restrict__ db,
                    float* __restrict__ acc) {
    int b = blockIdx.x >> 7;
    int m0 = (blockIdx.x & 127) * 4;
    __shared__ float w_s[4][128];
    __shared__ float red_s2[4];
    int tid = threadIdx.x;
    if (tid < 128) {
#pragma unroll
        for (int mm = 0; mm < 4; ++mm) w_s[mm][tid] = dw[(m0 + mm) * 128 + tid];
    }
    __syncthreads();
    float lsum = 0.f;
#pragma unroll
    for (int rep = 0; rep < 2; ++rep) {
        int dd = tid + rep * 256;
        float a0 = 0, a1 = 0, a2 = 0, a3 = 0;
        for (int c = 0; c < 128; ++c) {
            float cv = cmem_new[(size_t)b * 65536 + c * 512 + dd];
            a0 += cv * w_s[0][c]; a1 += cv * w_s[1][c];
            a2 += cv * w_s[2][c]; a3 += cv * w_s[3][c];
        }
#pragma unroll
        for (int mm = 0; mm < 4; ++mm) {
            float a = (mm == 0) ? a0 : (mm == 1) ? a1 : (mm == 2) ? a2 : a3;
            float d = mem[(size_t)(b * 512 + m0 + mm) * 512 + dd] - (a + db[m0 + mm]);
            lsum += d * d;
        }
    }
    lsum = wave_red_sum(lsum);
    if ((tid & 63) == 0) red_s2[tid >> 6] = lsum;
    __syncthreads();
    if (tid == 0) atomicAdd(acc, red_s2[0] + red_s2[1] + red_s2[2] + red_s2[3]);
}

__global__ void finalize(const float* __restrict__ acc, float* __restrict__ out) {
    if (threadIdx.x == 0) {
        out[0] = acc[0] * (1.f / 2097152.f);
        out[1] = acc[1] * (1.f / 2097152.f);
    }
}

// ---------------- launch ----------------
extern "C" void kernel_launch(void* const* d_in, const int* in_sizes, int n_in,
                              void* d_out, int out_size, void* d_ws, size_t ws_size,
                              hipStream_t stream) {
    const float* x      = (const float*)d_in[0];
    const float* mem    = (const float*)d_in[1];
    const float* cmem   = (const float*)d_in[2];
    const float* Wq     = (const float*)d_in[3];
    const float* Wkv    = (const float*)d_in[4];
    const float* Wo     = (const float*)d_in[5];
    const float* bo     = (const float*)d_in[6];
    const float* conv_w = (const float*)d_in[7];
    const float* conv_b = (const float*)d_in[8];
    const float* deconv_w = (const float*)d_in[9];
    const float* deconv_b = (const float*)d_in[10];
    float* out = (float*)d_out;

    char* w = (char*)d_ws;
    auto alloc = [&](size_t bytes) { char* p = w; w += (bytes + 255) & ~255ull; return p; };
    u16* Wq_bf   = (u16*)alloc(262144 * 2);
    u16* Wkv_bf  = (u16*)alloc(524288 * 2);
    u16* Wo_bf   = (u16*)alloc(262144 * 2);
    u16* cw2_bf  = (u16*)alloc(1048576 * 2);
    u16* kvin_bf = (u16*)alloc(4718592 * 2);
    u16* q_bf    = (u16*)alloc(2097152 * 2);
    u16* kv_bf   = (u16*)alloc(9437184 * 2);
    u16* comp_bf = (u16*)alloc(524288 * 2);
    u16* ckv_bf  = (u16*)alloc(1048576 * 2);
    u16* vTm     = (u16*)alloc(4718592 * 2);
    u16* vTc     = (u16*)alloc(524288 * 2);
    u16* attn_bf = (u16*)alloc(2097152 * 2);
    float* part  = (float*)alloc(8 * 524288 * 4);
    float* accs  = (float*)alloc(256);

    float* logits_o  = out;
    float* newmem_o  = out + 2097152;
    float* newcmem_o = out + 4194304;
    float* scalars_o = out + 4718592;

    prep_kernel<<<6656, 256, 0, stream>>>(x, mem, cmem, Wq, Wkv, Wo, conv_w,
                                          kvin_bf, Wq_bf, Wkv_bf, Wo_bf, cw2_bf, accs);
    hipMemcpyAsync(newmem_o, x, 2097152 * sizeof(float), hipMemcpyDeviceToDevice, stream);

    // q projection: A = kvin x-slice
    gemm_bt<<<dim3(32, 4), 256, 0, stream>>>(kvin_bf + 327680, 512, 512, 589824,
                                             Wq_bf, 512, 512,
                                             nullptr, 0, nullptr, q_bf, 512, nullptr);
    // kv projection: A = kvin full
    gemm_bt<<<dim3(72, 8), 256, 0, stream>>>(kvin_bf, 512, 9216, 0,
                                             Wkv_bf, 512, 512,
                                             nullptr, 0, nullptr, kv_bf, 1024, nullptr);
    transpose_v<<<dim3(18, 64), 256, 0, stream>>>(kv_bf, vTm, KVLEN);

    // conv compression as split-K GEMM over kvin mem-slice
    gemm_bt<<<dim3(8, 4, 8), 256, 0, stream>>>(kvin_bf + 65536, 2048, 128, 589824,
                                               cw2_bf, 2048, 256,
                                               part, 524288, nullptr, nullptr, 512, nullptr);
    conv_reduce<<<512, 256, 0, stream>>>(part, conv_b, newcmem_o, comp_bf);

    gemm_bt<<<dim3(8, 8), 256, 0, stream>>>(comp_bf, 512, 1024, 0,
                                            Wkv_bf, 512, 512,
                                            nullptr, 0, nullptr, ckv_bf, 1024, nullptr);
    transpose_v<<<dim3(2, 64), 256, 0, stream>>>(ckv_bf, vTc, 128);

    // main attention + output projection
    attn_main2<<<dim3(4, 64), 256, 0, stream>>>(q_bf, kv_bf, vTm, attn_bf);
    gemm_bt<<<dim3(32, 4), 256, 0, stream>>>(attn_bf, 512, 4096, 0,
                                             Wo_bf, 512, 512,
                                             nullptr, 0, logits_o, nullptr, 512, bo);

    // aux + ae losses
    attn_aux2<<<dim3(4, 64), 256, 0, stream>>>(q_bf, kv_bf, vTm, ckv_bf, vTc, accs);
    ae_loss_kernel<<<1024, 256, 0, stream>>>(newcmem_o, mem, deconv_w, deconv_b, accs + 1);
    finalize<<<1, 64, 0, stream>>>(accs, scalars_o);
}

// Round 4
// 190.585 us; speedup vs baseline: 1.6018x; 1.0362x over previous
//
#include <hip/hip_runtime.h>

typedef __bf16 bf16x8 __attribute__((ext_vector_type(8)));
typedef float f32x4 __attribute__((ext_vector_type(4)));
typedef float f32x16 __attribute__((ext_vector_type(16)));
typedef unsigned short u16;
typedef unsigned int u32;

#define TLEN 512
#define DMODEL 512
#define DH 64
#define KVLEN 1152
#define TOTALMEM 640

__device__ inline u16 f2b(float f) {
    union { float f; u32 u; } x; x.f = f;
    u32 u = x.u;
    return (u16)((u + 0x7FFFu + ((u >> 16) & 1u)) >> 16);
}

__device__ inline float wave_red_sum(float v) {
#pragma unroll
    for (int off = 1; off < 64; off <<= 1) v += __shfl_xor(v, off);
    return v;
}

__device__ inline void gload16(const u16* g, u16* l) {
    __builtin_amdgcn_global_load_lds((const __attribute__((address_space(1))) void*)g,
                                     (__attribute__((address_space(3))) void*)l, 16, 0, 0);
}

__device__ __forceinline__ u32 cvtpk_bf16(float lo, float hi) {
    u32 r;
    asm("v_cvt_pk_bf16_f32 %0, %1, %2" : "=v"(r) : "v"(lo), "v"(hi));
    return r;
}

// ---------------- fused prep: kvin build + new_mem passthrough + weight converts + acc zero
__global__ __launch_bounds__(256)
void prep_kernel(const float* __restrict__ x, const float* __restrict__ mem,
                 const float* __restrict__ cmem, const float* __restrict__ Wq,
                 const float* __restrict__ Wkv, const float* __restrict__ Wo,
                 const float* __restrict__ cw,
                 u16* __restrict__ kvin, u16* __restrict__ wq_b, u16* __restrict__ wkv_b,
                 u16* __restrict__ wo_b, u16* __restrict__ cw2,
                 float* __restrict__ newmem, float* __restrict__ accs) {
    int idx = blockIdx.x * 256 + threadIdx.x;
    if (idx == 0) { accs[0] = 0.f; accs[1] = 0.f; accs[2] = 0.f; accs[3] = 0.f; }
    int e = idx * 4;
    float4 v;
    u16* o;
    if (e < 4718592) {
        int row = e >> 9, col = e & 511;
        int b = row / KVLEN, p = row - b * KVLEN;
        const float* src;
        if (p < 128)       src = cmem + ((size_t)(b * 128 + p)) * 512 + col;
        else if (p < 640)  src = mem  + ((size_t)(b * 512 + (p - 128))) * 512 + col;
        else               src = x    + ((size_t)(b * 512 + (p - 640))) * 512 + col;
        v = *(const float4*)src;
        o = kvin + e;
        if (p >= 640)
            *(float4*)(newmem + ((size_t)(b * 512 + (p - 640)) * 512 + col)) = v;
    } else if (e < 4980736) {
        int t = e - 4718592; v = *(const float4*)(Wq + t); o = wq_b + t;
    } else if (e < 5505024) {
        int t = e - 4980736; v = *(const float4*)(Wkv + t); o = wkv_b + t;
    } else if (e < 5767168) {
        int t = e - 5505024; v = *(const float4*)(Wo + t); o = wo_b + t;
    } else {
        int t = e - 5767168;
        int oo = t >> 11, rem = t & 2047, tt = rem >> 9, ii = rem & 511;
        const float* s0 = cw + oo * 2048 + tt;
        v.x = s0[(ii + 0) * 4]; v.y = s0[(ii + 1) * 4];
        v.z = s0[(ii + 2) * 4]; v.w = s0[(ii + 3) * 4];
        o = cw2 + t;
    }
    o[0] = f2b(v.x); o[1] = f2b(v.y); o[2] = f2b(v.z); o[3] = f2b(v.w);
}

// ---------------- generic bf16 MFMA GEMM device body (m97 staging)
__device__ __forceinline__ void gemm_dev(
    const u16* __restrict__ A, int lda, int rowsPerB, long long bstride,
    const u16* __restrict__ Bt, int ldb, int Kb,
    float* __restrict__ Cpart, int partStride,
    float* __restrict__ Cf, u16* __restrict__ Cb, int ldc,
    const float* __restrict__ bias,
    int bx, int by, int bz, u16* As, u16* Bs) {
    const int tid = threadIdx.x;
    const int lane = tid & 63, wave = tid >> 6;
    const int wr = (wave >> 1) * 64, wc = (wave & 1) * 64;
    const int fr = lane & 15, fg = lane >> 4;
    const int arow0 = bx * 128;
    const int brow0 = by * 128;
    const int k0start = bz * Kb;

    const int lrow = lane >> 2;
    const int lcol = (lane & 3) * 8;
    const u16* gA[2]; const u16* gB[2];
#pragma unroll
    for (int i = 0; i < 2; ++i) {
        int r = wave * 32 + i * 16 + lrow;
        int gr = arow0 + r;
        int bb = gr / rowsPerB;
        int lr = gr - bb * rowsPerB;
        gA[i] = A + (size_t)bb * bstride + (size_t)lr * lda + k0start + lcol;
        gB[i] = Bt + (size_t)(brow0 + r) * ldb + k0start + lcol;
    }
    u16* lA0 = &As[(wave * 32) * 32];
    u16* lA1 = &As[(wave * 32 + 16) * 32];
    u16* lB0 = &Bs[(wave * 32) * 32];
    u16* lB1 = &Bs[(wave * 32 + 16) * 32];

    f32x4 acc[4][4] = {};
    for (int k = 0; k < Kb; k += 32) {
        __syncthreads();
        gload16(gA[0] + k, lA0);
        gload16(gA[1] + k, lA1);
        gload16(gB[0] + k, lB0);
        gload16(gB[1] + k, lB1);
        __syncthreads();
        bf16x8 af[4], bfr[4];
#pragma unroll
        for (int m = 0; m < 4; ++m) af[m] = *(bf16x8*)&As[(wr + m * 16 + fr) * 32 + fg * 8];
#pragma unroll
        for (int n = 0; n < 4; ++n) bfr[n] = *(bf16x8*)&Bs[(wc + n * 16 + fr) * 32 + fg * 8];
#pragma unroll
        for (int m = 0; m < 4; ++m)
#pragma unroll
            for (int n = 0; n < 4; ++n)
                acc[m][n] = __builtin_amdgcn_mfma_f32_16x16x32_bf16(af[m], bfr[n], acc[m][n], 0, 0, 0);
    }

#pragma unroll
    for (int m = 0; m < 4; ++m)
#pragma unroll
        for (int n = 0; n < 4; ++n)
#pragma unroll
            for (int r = 0; r < 4; ++r) {
                int row = arow0 + wr + m * 16 + fg * 4 + r;
                int col = brow0 + wc + n * 16 + fr;
                float v = acc[m][n][r];
                if (Cpart) {
                    Cpart[(size_t)bz * partStride + (size_t)row * ldc + col] = v;
                } else {
                    if (bias) v += bias[col];
                    if (Cf) Cf[(size_t)row * ldc + col] = v;
                    if (Cb) Cb[(size_t)row * ldc + col] = f2b(v);
                }
            }
}

// ---------------- fused q + kv + conv GEMMs (independent, one 960-block dispatch)
__global__ __launch_bounds__(256)
void gemm3(const u16* __restrict__ kvin, const u16* __restrict__ wq,
           const u16* __restrict__ wkv, const u16* __restrict__ cw2,
           u16* __restrict__ q_bf, u16* __restrict__ kv_bf, float* __restrict__ part) {
    __shared__ u16 As[128 * 32];
    __shared__ u16 Bs[128 * 32];
    int id = blockIdx.x;
    if (id < 128) {
        gemm_dev(kvin + 327680, 512, 512, 589824, wq, 512, 512,
                 nullptr, 0, nullptr, q_bf, 512, nullptr,
                 id & 31, id >> 5, 0, As, Bs);
    } else if (id < 704) {
        int t = id - 128;
        gemm_dev(kvin, 512, 9216, 0, wkv, 512, 512,
                 nullptr, 0, nullptr, kv_bf, 1024, nullptr,
                 t % 72, t / 72, 0, As, Bs);
    } else {
        int t = id - 704;
        gemm_dev(kvin + 65536, 2048, 128, 589824, cw2, 2048, 256,
                 part, 524288, nullptr, nullptr, 512, nullptr,
                 t & 7, (t >> 3) & 3, t >> 5, As, Bs);
    }
}

// ---------------- standalone GEMM (ckv only)
__global__ __launch_bounds__(256)
void gemm_bt(const u16* __restrict__ A, int lda, int rowsPerB, long long bstride,
             const u16* __restrict__ Bt, int ldb, int Kb,
             u16* __restrict__ Cb, int ldc) {
    __shared__ u16 As[128 * 32];
    __shared__ u16 Bs[128 * 32];
    gemm_dev(A, lda, rowsPerB, bstride, Bt, ldb, Kb, nullptr, 0, nullptr, Cb, ldc,
             nullptr, blockIdx.x, blockIdx.y, 0, As, Bs);
}

// ---------------- split-K reduce for conv
__global__ __launch_bounds__(256)
void conv_reduce(const float* __restrict__ part, const float* __restrict__ cb,
                 float* __restrict__ outf, u16* __restrict__ outb) {
    int idx = (blockIdx.x * 256 + threadIdx.x) * 4;
    float4 s = *(const float4*)(part + idx);
#pragma unroll
    for (int sp = 1; sp < 8; ++sp) {
        float4 p = *(const float4*)(part + (size_t)sp * 524288 + idx);
        s.x += p.x; s.y += p.y; s.z += p.z; s.w += p.w;
    }
    float4 bb = *(const float4*)(cb + (idx & 511));
    s.x += bb.x; s.y += bb.y; s.z += bb.z; s.w += bb.w;
    *(float4*)(outf + idx) = s;
    outb[idx + 0] = f2b(s.x); outb[idx + 1] = f2b(s.y);
    outb[idx + 2] = f2b(s.z); outb[idx + 3] = f2b(s.w);
}

// ---------------- V transposes (vTm + vTc in one dispatch)
__device__ __forceinline__ void transpose_dev(const u16* __restrict__ kv,
                                              u16* __restrict__ vT, int rowsPerB,
                                              int jt, int bh, u16* t_s) {
    int b = bh >> 3, h = bh & 7;
    int tid = threadIdx.x;
    int jr = tid >> 2, c0 = (tid & 3) * 16;
    const u16* g = kv + (size_t)(b * rowsPerB + jt * 64 + jr) * 1024 + 512 + h * DH + c0;
#pragma unroll
    for (int u = 0; u < 16; ++u) t_s[jr * 65 + c0 + u] = g[u];
    __syncthreads();
    int dh = tid >> 2, j0 = (tid & 3) * 16;
    union { u16 us[8]; bf16x8 v8; } o1, o2;
#pragma unroll
    for (int u = 0; u < 8; ++u) {
        o1.us[u] = t_s[(j0 + u) * 65 + dh];
        o2.us[u] = t_s[(j0 + 8 + u) * 65 + dh];
    }
    u16* o = vT + (size_t)(bh * DH + dh) * rowsPerB + jt * 64 + j0;
    *(bf16x8*)o = o1.v8;
    *(bf16x8*)(o + 8) = o2.v8;
}

__global__ __launch_bounds__(256)
void transpose2(const u16* __restrict__ kv, u16* __restrict__ vTm_,
                const u16* __restrict__ ckv, u16* __restrict__ vTc_) {
    __shared__ u16 t_s[64 * 65];
    int bx = blockIdx.x, bh = blockIdx.y;
    if (bx < 18) transpose_dev(kv, vTm_, KVLEN, bx, bh, t_s);
    else         transpose_dev(ckv, vTc_, 128, bx - 18, bh, t_s);
}

// ================= attention: swapped-QK, in-register softmax (r3, unchanged) =================
template <bool MASK>
__device__ __forceinline__ void attn_pass(
    const u16* __restrict__ kbase, int kstride,
    const u16* __restrict__ vbase, int vstride,
    int njt, int tid, int iq_min,
    const bf16x8* qf, u16* k_s, u16* v_s,
    f32x16& o0, f32x16& o1, float& m_run, float& l_run)
{
    const int lane = tid & 63;
    const int c31 = lane & 31;
    const int hi = lane >> 5;
    const int hi4 = hi << 2;
    const int srow = tid >> 2, ssl = tid & 3;
    const int kwa = srow * 64 + ((ssl ^ (srow & 7)) << 3);
    const int kwb = srow * 64 + (((ssl + 4) ^ (srow & 7)) << 3);
    const int iq = iq_min + c31;

    int krd[2][4];
#pragma unroll
    for (int jsub = 0; jsub < 2; ++jsub) {
        int row = jsub * 32 + c31;
#pragma unroll
        for (int ks = 0; ks < 4; ++ks)
            krd[jsub][ks] = row * 64 + (((2 * ks + hi) ^ (row & 7)) << 3);
    }
    int vrd[2][4];
#pragma unroll
    for (int half = 0; half < 2; ++half) {
        int row = half * 32 + c31;
#pragma unroll
        for (int s = 0; s < 4; ++s)
            vrd[half][s] = row * 64 + (((2 * s + hi) ^ (row & 7)) << 3);
    }

    float4 lk0, lk1, lv0, lv1;
#define AT_LOAD(T) { \
        const u16* gk = kbase + (size_t)((T) * 64 + srow) * kstride + ssl * 8; \
        lk0 = *(const float4*)gk; lk1 = *(const float4*)(gk + 32); \
        const u16* gv = vbase + (size_t)srow * vstride + (T) * 64 + ssl * 8; \
        lv0 = *(const float4*)gv; lv1 = *(const float4*)(gv + 32); }
#define AT_STORE(B) { \
        u16* kd = k_s + (B) * 4096; u16* vd = v_s + (B) * 4096; \
        *(float4*)(kd + kwa) = lk0; *(float4*)(kd + kwb) = lk1; \
        *(float4*)(vd + kwa) = lv0; *(float4*)(vd + kwb) = lv1; }

    AT_LOAD(0); AT_STORE(0);
    __syncthreads();

    for (int t = 0; t < njt; ++t) {
        const int cur = t & 1;
        if (t + 1 < njt) AT_LOAD(t + 1);
        const u16* ks_ = k_s + cur * 4096;
        const u16* vs_ = v_s + cur * 4096;

        f32x16 sA = {}, sB = {};
#pragma unroll
        for (int ks = 0; ks < 4; ++ks) {
            bf16x8 a0 = *(const bf16x8*)&ks_[krd[0][ks]];
            sA = __builtin_amdgcn_mfma_f32_32x32x16_bf16(a0, qf[ks], sA, 0, 0, 0);
        }
#pragma unroll
        for (int ks = 0; ks < 4; ++ks) {
            bf16x8 a1 = *(const bf16x8*)&ks_[krd[1][ks]];
            sB = __builtin_amdgcn_mfma_f32_32x32x16_bf16(a1, qf[ks], sB, 0, 0, 0);
        }
        if (MASK) {
            if (t * 64 + 63 > iq_min + TOTALMEM) {
#pragma unroll
                for (int r = 0; r < 16; ++r) {
                    int rj = (r & 3) + 8 * (r >> 2) + hi4;
                    if (t * 64 + rj > iq + TOTALMEM) sA[r] = -1e30f;
                    if (t * 64 + 32 + rj > iq + TOTALMEM) sB[r] = -1e30f;
                }
            }
        }
        float tmax = sA[0];
#pragma unroll
        for (int r = 1; r < 16; ++r) tmax = fmaxf(tmax, sA[r]);
#pragma unroll
        for (int r = 0; r < 16; ++r) tmax = fmaxf(tmax, sB[r]);
        tmax = fmaxf(tmax, __shfl_xor(tmax, 32));
        tmax *= 0.125f;
        if (__any(tmax > m_run + 8.0f)) {
            float m_new = fmaxf(m_run, tmax);
            float scl = __expf(m_run - m_new);
            m_run = m_new;
            l_run *= scl;
#pragma unroll
            for (int r = 0; r < 16; ++r) {
                float sc = __shfl(scl, (r & 3) + 8 * (r >> 2) + hi4);
                o0[r] *= sc; o1[r] *= sc;
            }
        }
        const float negm = -m_run;
        float ps = 0.f;
#pragma unroll
        for (int jsub = 0; jsub < 2; ++jsub) {
#pragma unroll
            for (int ksub = 0; ksub < 2; ++ksub) {
                float p0 = __expf(fmaf((jsub ? sB[ksub * 8 + 0] : sA[ksub * 8 + 0]), 0.125f, negm));
                float p1 = __expf(fmaf((jsub ? sB[ksub * 8 + 1] : sA[ksub * 8 + 1]), 0.125f, negm));
                float p2 = __expf(fmaf((jsub ? sB[ksub * 8 + 2] : sA[ksub * 8 + 2]), 0.125f, negm));
                float p3 = __expf(fmaf((jsub ? sB[ksub * 8 + 3] : sA[ksub * 8 + 3]), 0.125f, negm));
                float p4 = __expf(fmaf((jsub ? sB[ksub * 8 + 4] : sA[ksub * 8 + 4]), 0.125f, negm));
                float p5 = __expf(fmaf((jsub ? sB[ksub * 8 + 5] : sA[ksub * 8 + 5]), 0.125f, negm));
                float p6 = __expf(fmaf((jsub ? sB[ksub * 8 + 6] : sA[ksub * 8 + 6]), 0.125f, negm));
                float p7 = __expf(fmaf((jsub ? sB[ksub * 8 + 7] : sA[ksub * 8 + 7]), 0.125f, negm));
                ps += ((p0 + p1) + (p2 + p3)) + ((p4 + p5) + (p6 + p7));
                u32 X = cvtpk_bf16(p0, p1);
                u32 Z = cvtpk_bf16(p2, p3);
                u32 Y = cvtpk_bf16(p4, p5);
                u32 W = cvtpk_bf16(p6, p7);
                auto s1 = __builtin_amdgcn_permlane32_swap(X, Y, false, false);
                auto s2 = __builtin_amdgcn_permlane32_swap(Z, W, false, false);
                union { u32 w[4]; bf16x8 v; } fa;
                fa.w[0] = (u32)s1[0]; fa.w[1] = (u32)s2[0];
                fa.w[2] = (u32)s1[1]; fa.w[3] = (u32)s2[1];
                bf16x8 bv0 = *(const bf16x8*)&vs_[vrd[0][jsub * 2 + ksub]];
                bf16x8 bv1 = *(const bf16x8*)&vs_[vrd[1][jsub * 2 + ksub]];
                o0 = __builtin_amdgcn_mfma_f32_32x32x16_bf16(fa.v, bv0, o0, 0, 0, 0);
                o1 = __builtin_amdgcn_mfma_f32_32x32x16_bf16(fa.v, bv1, o1, 0, 0, 0);
            }
        }
        ps += __shfl_xor(ps, 32);
        l_run += ps;
        if (t + 1 < njt) AT_STORE(cur ^ 1);
        __syncthreads();
    }
#undef AT_LOAD
#undef AT_STORE
}

__global__ __launch_bounds__(256)
void attn_main2(const u16* __restrict__ q_bf, const u16* __restrict__ kv,
                const u16* __restrict__ vT, u16* __restrict__ out_bf) {
    __shared__ u16 k_s[2 * 4096];
    __shared__ u16 v_s[2 * 4096];
    const int it = blockIdx.x, bh = blockIdx.y;
    const int b = bh >> 3, h = bh & 7;
    const int tid = threadIdx.x;
    const int w = tid >> 6, lane = tid & 63;
    const int c31 = lane & 31, hi4 = (lane >> 5) << 2;
    const int iwmin = it * 128 + w * 32;
    const int iq = iwmin + c31;

    bf16x8 qf[4];
#pragma unroll
    for (int ks = 0; ks < 4; ++ks)
        qf[ks] = *(const bf16x8*)&q_bf[(size_t)(b * TLEN + iq) * DMODEL + h * DH + ks * 16 + hi4 * 2];

    const u16* kbase = kv + (size_t)b * KVLEN * 1024 + h * DH;
    const u16* vbase = vT + (size_t)(bh * DH) * KVLEN;
    const int njt = ((it * 128 + 767) >> 6) + 1;

    f32x16 o0 = {}, o1 = {};
    float m_run = -1e30f, l_run = 0.f;
    attn_pass<true>(kbase, 1024, vbase, KVLEN, njt, tid, iwmin, qf, k_s, v_s, o0, o1, m_run, l_run);

    float linv = 1.0f / l_run;
#pragma unroll
    for (int r = 0; r < 16; ++r) {
        int R = (r & 3) + 8 * (r >> 2) + hi4;
        float li = __shfl(linv, R);
        int i = iwmin + R;
        u16* o = out_bf + (size_t)(b * TLEN + i) * DMODEL + h * DH + c31;
        o[0]  = f2b(o0[r] * li);
        o[32] = f2b(o1[r] * li);
    }
}

// ---------------- fused tail: Wo GEMM + aux attention + ae loss + finalize
__global__ __launch_bounds__(256)
void tail_fused(const u16* __restrict__ attn_bf, const u16* __restrict__ wo_b,
                const float* __restrict__ bo, float* __restrict__ logits,
                const u16* __restrict__ q_bf, const u16* __restrict__ kv,
                const u16* __restrict__ vTm_, const u16* __restrict__ ckv,
                const u16* __restrict__ vTc_,
                const float* __restrict__ cmem_new, const float* __restrict__ mem,
                const float* __restrict__ dw, const float* __restrict__ db,
                float* __restrict__ accs, float* __restrict__ scal_out) {
    __shared__ __align__(16) char smem[32800];
    const int id = blockIdx.x;
    const int tid = threadIdx.x;
    bool contrib = false;

    if (id < 128) {
        // ---- Wo output projection
        u16* As = (u16*)smem;
        u16* Bs = (u16*)(smem + 8192);
        gemm_dev(attn_bf, 512, 4096, 0, wo_b, 512, 512,
                 nullptr, 0, logits, nullptr, 512, bo, id & 31, id >> 5, 0, As, Bs);
    } else if (id < 384) {
        // ---- aux attention (mem pass vs cmem pass, diff^2)
        u16* k_s = (u16*)smem;
        u16* v_s = (u16*)(smem + 16384);
        float* red_s = (float*)(smem + 32768);
        const int t2 = id - 128;
        const int it = t2 & 3, bh = t2 >> 2;
        const int b = bh >> 3, h = bh & 7;
        const int w = tid >> 6, lane = tid & 63;
        const int c31 = lane & 31, hi4 = (lane >> 5) << 2;
        const int iwmin = it * 128 + w * 32;
        const int iq = iwmin + c31;

        bf16x8 qf[4];
#pragma unroll
        for (int ks = 0; ks < 4; ++ks)
            qf[ks] = *(const bf16x8*)&q_bf[(size_t)(b * TLEN + iq) * DMODEL + h * DH + ks * 16 + hi4 * 2];

        f32x16 o0 = {}, o1 = {};
        float m_run = -1e30f, l_run = 0.f;
        attn_pass<false>(kv + (size_t)(b * KVLEN + 128) * 1024 + h * DH, 1024,
                         vTm_ + (size_t)(bh * DH) * KVLEN + 128, KVLEN, 8,
                         tid, 0, qf, k_s, v_s, o0, o1, m_run, l_run);
        float n0[16], n1[16];
        {
            float linv = 1.0f / l_run;
#pragma unroll
            for (int r = 0; r < 16; ++r) {
                float li = __shfl(linv, (r & 3) + 8 * (r >> 2) + hi4);
                n0[r] = o0[r] * li;
                n1[r] = o1[r] * li;
            }
        }
        f32x16 c0 = {}, c1 = {};
        m_run = -1e30f; l_run = 0.f;
        attn_pass<false>(ckv + (size_t)(b * 128) * 1024 + h * DH, 1024,
                         vTc_ + (size_t)(bh * DH) * 128, 128, 2,
                         tid, 0, qf, k_s, v_s, c0, c1, m_run, l_run);
        float lsum = 0.f;
        {
            float linv = 1.0f / l_run;
#pragma unroll
            for (int r = 0; r < 16; ++r) {
                float li = __shfl(linv, (r & 3) + 8 * (r >> 2) + hi4);
                float d0 = n0[r] - c0[r] * li;
                float d1 = n1[r] - c1[r] * li;
                lsum += d0 * d0 + d1 * d1;
            }
        }
        lsum = wave_red_sum(lsum);
        if (lane == 0) red_s[w] = lsum;
        __syncthreads();
        if (tid == 0) atomicAdd(accs, red_s[0] + red_s[1] + red_s[2] + red_s[3]);
        contrib = true;
    } else {
        // ---- ae loss
        float* w_s = (float*)smem;                 // [4][128]
        float* red2 = (float*)(smem + 2048);
        const int t3 = id - 384;
        const int b = t3 >> 7;
        const int m0 = (t3 & 127) * 4;
        if (tid < 128) {
#pragma unroll
            for (int mm = 0; mm < 4; ++mm) w_s[mm * 128 + tid] = dw[(m0 + mm) * 128 + tid];
        }
        __syncthreads();
        float lsum = 0.f;
#pragma unroll
        for (int rep = 0; rep < 2; ++rep) {
            int dd = tid + rep * 256;
            float a0 = 0, a1 = 0, a2 = 0, a3 = 0;
            for (int c = 0; c < 128; ++c) {
                float cv = cmem_new[(size_t)b * 65536 + c * 512 + dd];
                a0 += cv * w_s[0 * 128 + c]; a1 += cv * w_s[1 * 128 + c];
                a2 += cv * w_s[2 * 128 + c]; a3 += cv * w_s[3 * 128 + c];
            }
#pragma unroll
            for (int mm = 0; mm < 4; ++mm) {
                float a = (mm == 0) ? a0 : (mm == 1) ? a1 : (mm == 2) ? a2 : a3;
                float d = mem[(size_t)(b * 512 + m0 + mm) * 512 + dd] - (a + db[m0 + mm]);
                lsum += d * d;
            }
        }
        lsum = wave_red_sum(lsum);
        if ((tid & 63) == 0) red2[tid >> 6] = lsum;
        __syncthreads();
        if (tid == 0) atomicAdd(accs + 1, red2[0] + red2[1] + red2[2] + red2[3]);
        contrib = true;
    }

    // completion-counter finalize (aux 256 + ae 1024 = 1280 contributors)
    if (contrib && tid == 0) {
        __threadfence();
        u32 c = atomicAdd((u32*)(accs + 2), 1u);
        if (c == 1279u) {
            float a0 = atomicAdd(accs + 0, 0.f);
            float a1 = atomicAdd(accs + 1, 0.f);
            scal_out[0] = a0 * (1.f / 2097152.f);
            scal_out[1] = a1 * (1.f / 2097152.f);
        }
    }
}

// ---------------- launch ----------------
extern "C" void kernel_launch(void* const* d_in, const int* in_sizes, int n_in,
                              void* d_out, int out_size, void* d_ws, size_t ws_size,
                              hipStream_t stream) {
    const float* x      = (const float*)d_in[0];
    const float* mem    = (const float*)d_in[1];
    const float* cmem   = (const float*)d_in[2];
    const float* Wq     = (const float*)d_in[3];
    const float* Wkv    = (const float*)d_in[4];
    const float* Wo     = (const float*)d_in[5];
    const float* bo     = (const float*)d_in[6];
    const float* conv_w = (const float*)d_in[7];
    const float* conv_b = (const float*)d_in[8];
    const float* deconv_w = (const float*)d_in[9];
    const float* deconv_b = (const float*)d_in[10];
    float* out = (float*)d_out;

    char* w = (char*)d_ws;
    auto alloc = [&](size_t bytes) { char* p = w; w += (bytes + 255) & ~255ull; return p; };
    u16* Wq_bf   = (u16*)alloc(262144 * 2);
    u16* Wkv_bf  = (u16*)alloc(524288 * 2);
    u16* Wo_bf   = (u16*)alloc(262144 * 2);
    u16* cw2_bf  = (u16*)alloc(1048576 * 2);
    u16* kvin_bf = (u16*)alloc(4718592 * 2);
    u16* q_bf    = (u16*)alloc(2097152 * 2);
    u16* kv_bf   = (u16*)alloc(9437184 * 2);
    u16* comp_bf = (u16*)alloc(524288 * 2);
    u16* ckv_bf  = (u16*)alloc(1048576 * 2);
    u16* vTm     = (u16*)alloc(4718592 * 2);
    u16* vTc     = (u16*)alloc(524288 * 2);
    u16* attn_bf = (u16*)alloc(2097152 * 2);
    float* part  = (float*)alloc(8 * 524288 * 4);
    float* accs  = (float*)alloc(256);

    float* logits_o  = out;
    float* newmem_o  = out + 2097152;
    float* newcmem_o = out + 4194304;
    float* scalars_o = out + 4718592;

    // 1. prep: kvin + new_mem + weight converts + acc/ctr zero
    prep_kernel<<<6656, 256, 0, stream>>>(x, mem, cmem, Wq, Wkv, Wo, conv_w,
                                          kvin_bf, Wq_bf, Wkv_bf, Wo_bf, cw2_bf,
                                          newmem_o, accs);

    // 2. fused q + kv + conv GEMMs (960 blocks)
    gemm3<<<960, 256, 0, stream>>>(kvin_bf, Wq_bf, Wkv_bf, cw2_bf, q_bf, kv_bf, part);

    // 3. conv split-K reduce -> new_cmem (f32) + comp (bf16)
    conv_reduce<<<512, 256, 0, stream>>>(part, conv_b, newcmem_o, comp_bf);

    // 4. ckv projection
    gemm_bt<<<dim3(8, 8), 256, 0, stream>>>(comp_bf, 512, 1024, 0, Wkv_bf, 512, 512,
                                            ckv_bf, 1024);

    // 5. both V transposes
    transpose2<<<dim3(20, 64), 256, 0, stream>>>(kv_bf, vTm, ckv_bf, vTc);

    // 6. main causal attention
    attn_main2<<<dim3(4, 64), 256, 0, stream>>>(q_bf, kv_bf, vTm, attn_bf);

    // 7. fused tail: Wo GEMM + aux attention + ae loss + finalize
    tail_fused<<<1408, 256, 0, stream>>>(attn_bf, Wo_bf, bo, logits_o,
                                         q_bf, kv_bf, vTm, ckv_bf, vTc,
                                         newcmem_o, mem, deconv_w, deconv_b,
                                         accs, scalars_o);
}

// Round 5
// 164.804 us; speedup vs baseline: 1.8524x; 1.1564x over previous
//
#include <hip/hip_runtime.h>

typedef __bf16 bf16x8 __attribute__((ext_vector_type(8)));
typedef float f32x4 __attribute__((ext_vector_type(4)));
typedef float f32x16 __attribute__((ext_vector_type(16)));
typedef unsigned short u16;
typedef unsigned int u32;

#define TLEN 512
#define DMODEL 512
#define DH 64
#define KVLEN 1152
#define TOTALMEM 640

__device__ inline u16 f2b(float f) {
    union { float f; u32 u; } x; x.f = f;
    u32 u = x.u;
    return (u16)((u + 0x7FFFu + ((u >> 16) & 1u)) >> 16);
}

__device__ inline float wave_red_sum(float v) {
#pragma unroll
    for (int off = 1; off < 64; off <<= 1) v += __shfl_xor(v, off);
    return v;
}

__device__ inline void gload16(const u16* g, u16* l) {
    __builtin_amdgcn_global_load_lds((const __attribute__((address_space(1))) void*)g,
                                     (__attribute__((address_space(3))) void*)l, 16, 0, 0);
}

__device__ __forceinline__ u32 cvtpk_bf16(float lo, float hi) {
    u32 r;
    asm("v_cvt_pk_bf16_f32 %0, %1, %2" : "=v"(r) : "v"(lo), "v"(hi));
    return r;
}

// ---------------- fused prep: kvin build + new_mem passthrough + weight converts + acc zero
__global__ __launch_bounds__(256)
void prep_kernel(const float* __restrict__ x, const float* __restrict__ mem,
                 const float* __restrict__ cmem, const float* __restrict__ Wq,
                 const float* __restrict__ Wkv, const float* __restrict__ Wo,
                 const float* __restrict__ cw,
                 u16* __restrict__ kvin, u16* __restrict__ wq_b, u16* __restrict__ wkv_b,
                 u16* __restrict__ wo_b, u16* __restrict__ cw2,
                 float* __restrict__ newmem, float* __restrict__ accs) {
    int idx = blockIdx.x * 256 + threadIdx.x;
    if (idx == 0) { accs[0] = 0.f; accs[1] = 0.f; accs[2] = 0.f; accs[3] = 0.f; }
    int e = idx * 4;
    float4 v;
    u16* o;
    if (e < 4718592) {
        int row = e >> 9, col = e & 511;
        int b = row / KVLEN, p = row - b * KVLEN;
        const float* src;
        if (p < 128)       src = cmem + ((size_t)(b * 128 + p)) * 512 + col;
        else if (p < 640)  src = mem  + ((size_t)(b * 512 + (p - 128))) * 512 + col;
        else               src = x    + ((size_t)(b * 512 + (p - 640))) * 512 + col;
        v = *(const float4*)src;
        o = kvin + e;
        if (p >= 640)
            *(float4*)(newmem + ((size_t)(b * 512 + (p - 640)) * 512 + col)) = v;
    } else if (e < 4980736) {
        int t = e - 4718592; v = *(const float4*)(Wq + t); o = wq_b + t;
    } else if (e < 5505024) {
        int t = e - 4980736; v = *(const float4*)(Wkv + t); o = wkv_b + t;
    } else if (e < 5767168) {
        int t = e - 5505024; v = *(const float4*)(Wo + t); o = wo_b + t;
    } else {
        int t = e - 5767168;
        int oo = t >> 11, rem = t & 2047, tt = rem >> 9, ii = rem & 511;
        const float* s0 = cw + oo * 2048 + tt;
        v.x = s0[(ii + 0) * 4]; v.y = s0[(ii + 1) * 4];
        v.z = s0[(ii + 2) * 4]; v.w = s0[(ii + 3) * 4];
        o = cw2 + t;
    }
    o[0] = f2b(v.x); o[1] = f2b(v.y); o[2] = f2b(v.z); o[3] = f2b(v.w);
}

// ---------------- generic bf16 MFMA GEMM device body (m97 staging)
__device__ __forceinline__ void gemm_dev(
    const u16* __restrict__ A, int lda, int rowsPerB, long long bstride,
    const u16* __restrict__ Bt, int ldb, int Kb,
    float* __restrict__ Cpart, int partStride,
    float* __restrict__ Cf, u16* __restrict__ Cb, int ldc,
    const float* __restrict__ bias,
    int bx, int by, int bz, u16* As, u16* Bs) {
    const int tid = threadIdx.x;
    const int lane = tid & 63, wave = tid >> 6;
    const int wr = (wave >> 1) * 64, wc = (wave & 1) * 64;
    const int fr = lane & 15, fg = lane >> 4;
    const int arow0 = bx * 128;
    const int brow0 = by * 128;
    const int k0start = bz * Kb;

    const int lrow = lane >> 2;
    const int lcol = (lane & 3) * 8;
    const u16* gA[2]; const u16* gB[2];
#pragma unroll
    for (int i = 0; i < 2; ++i) {
        int r = wave * 32 + i * 16 + lrow;
        int gr = arow0 + r;
        int bb = gr / rowsPerB;
        int lr = gr - bb * rowsPerB;
        gA[i] = A + (size_t)bb * bstride + (size_t)lr * lda + k0start + lcol;
        gB[i] = Bt + (size_t)(brow0 + r) * ldb + k0start + lcol;
    }
    u16* lA0 = &As[(wave * 32) * 32];
    u16* lA1 = &As[(wave * 32 + 16) * 32];
    u16* lB0 = &Bs[(wave * 32) * 32];
    u16* lB1 = &Bs[(wave * 32 + 16) * 32];

    f32x4 acc[4][4] = {};
    for (int k = 0; k < Kb; k += 32) {
        __syncthreads();
        gload16(gA[0] + k, lA0);
        gload16(gA[1] + k, lA1);
        gload16(gB[0] + k, lB0);
        gload16(gB[1] + k, lB1);
        __syncthreads();
        bf16x8 af[4], bfr[4];
#pragma unroll
        for (int m = 0; m < 4; ++m) af[m] = *(bf16x8*)&As[(wr + m * 16 + fr) * 32 + fg * 8];
#pragma unroll
        for (int n = 0; n < 4; ++n) bfr[n] = *(bf16x8*)&Bs[(wc + n * 16 + fr) * 32 + fg * 8];
#pragma unroll
        for (int m = 0; m < 4; ++m)
#pragma unroll
            for (int n = 0; n < 4; ++n)
                acc[m][n] = __builtin_amdgcn_mfma_f32_16x16x32_bf16(af[m], bfr[n], acc[m][n], 0, 0, 0);
    }

#pragma unroll
    for (int m = 0; m < 4; ++m)
#pragma unroll
        for (int n = 0; n < 4; ++n)
#pragma unroll
            for (int r = 0; r < 4; ++r) {
                int row = arow0 + wr + m * 16 + fg * 4 + r;
                int col = brow0 + wc + n * 16 + fr;
                float v = acc[m][n][r];
                if (Cpart) {
                    Cpart[(size_t)bz * partStride + (size_t)row * ldc + col] = v;
                } else {
                    if (bias) v += bias[col];
                    if (Cf) Cf[(size_t)row * ldc + col] = v;
                    if (Cb) Cb[(size_t)row * ldc + col] = f2b(v);
                }
            }
}

// ---------------- fused q + kv + conv GEMMs (independent, one 960-block dispatch)
__global__ __launch_bounds__(256)
void gemm3(const u16* __restrict__ kvin, const u16* __restrict__ wq,
           const u16* __restrict__ wkv, const u16* __restrict__ cw2,
           u16* __restrict__ q_bf, u16* __restrict__ kv_bf, float* __restrict__ part) {
    __shared__ u16 As[128 * 32];
    __shared__ u16 Bs[128 * 32];
    int id = blockIdx.x;
    if (id < 128) {
        gemm_dev(kvin + 327680, 512, 512, 589824, wq, 512, 512,
                 nullptr, 0, nullptr, q_bf, 512, nullptr,
                 id & 31, id >> 5, 0, As, Bs);
    } else if (id < 704) {
        int t = id - 128;
        gemm_dev(kvin, 512, 9216, 0, wkv, 512, 512,
                 nullptr, 0, nullptr, kv_bf, 1024, nullptr,
                 t % 72, t / 72, 0, As, Bs);
    } else {
        int t = id - 704;
        gemm_dev(kvin + 65536, 2048, 128, 589824, cw2, 2048, 256,
                 part, 524288, nullptr, nullptr, 512, nullptr,
                 t & 7, (t >> 3) & 3, t >> 5, As, Bs);
    }
}

// ---------------- standalone GEMM (ckv, Wo)
__global__ __launch_bounds__(256)
void gemm_full(const u16* __restrict__ A, int lda, int rowsPerB, long long bstride,
               const u16* __restrict__ Bt, int ldb, int Kb,
               float* __restrict__ Cf, u16* __restrict__ Cb, int ldc,
               const float* __restrict__ bias) {
    __shared__ u16 As[128 * 32];
    __shared__ u16 Bs[128 * 32];
    gemm_dev(A, lda, rowsPerB, bstride, Bt, ldb, Kb, nullptr, 0, Cf, Cb, ldc,
             bias, blockIdx.x, blockIdx.y, 0, As, Bs);
}

// ---------------- split-K reduce for conv
__global__ __launch_bounds__(256)
void conv_reduce(const float* __restrict__ part, const float* __restrict__ cb,
                 float* __restrict__ outf, u16* __restrict__ outb) {
    int idx = (blockIdx.x * 256 + threadIdx.x) * 4;
    float4 s = *(const float4*)(part + idx);
#pragma unroll
    for (int sp = 1; sp < 8; ++sp) {
        float4 p = *(const float4*)(part + (size_t)sp * 524288 + idx);
        s.x += p.x; s.y += p.y; s.z += p.z; s.w += p.w;
    }
    float4 bb = *(const float4*)(cb + (idx & 511));
    s.x += bb.x; s.y += bb.y; s.z += bb.z; s.w += bb.w;
    *(float4*)(outf + idx) = s;
    outb[idx + 0] = f2b(s.x); outb[idx + 1] = f2b(s.y);
    outb[idx + 2] = f2b(s.z); outb[idx + 3] = f2b(s.w);
}

// ---------------- V transposes (vTm + vTc in one dispatch)
__device__ __forceinline__ void transpose_dev(const u16* __restrict__ kv,
                                              u16* __restrict__ vT, int rowsPerB,
                                              int jt, int bh, u16* t_s) {
    int b = bh >> 3, h = bh & 7;
    int tid = threadIdx.x;
    int jr = tid >> 2, c0 = (tid & 3) * 16;
    const u16* g = kv + (size_t)(b * rowsPerB + jt * 64 + jr) * 1024 + 512 + h * DH + c0;
#pragma unroll
    for (int u = 0; u < 16; ++u) t_s[jr * 65 + c0 + u] = g[u];
    __syncthreads();
    int dh = tid >> 2, j0 = (tid & 3) * 16;
    union { u16 us[8]; bf16x8 v8; } o1, o2;
#pragma unroll
    for (int u = 0; u < 8; ++u) {
        o1.us[u] = t_s[(j0 + u) * 65 + dh];
        o2.us[u] = t_s[(j0 + 8 + u) * 65 + dh];
    }
    u16* o = vT + (size_t)(bh * DH + dh) * rowsPerB + jt * 64 + j0;
    *(bf16x8*)o = o1.v8;
    *(bf16x8*)(o + 8) = o2.v8;
}

__global__ __launch_bounds__(256)
void transpose2(const u16* __restrict__ kv, u16* __restrict__ vTm_,
                const u16* __restrict__ ckv, u16* __restrict__ vTc_) {
    __shared__ u16 t_s[64 * 65];
    int bx = blockIdx.x, bh = blockIdx.y;
    if (bx < 18) transpose_dev(kv, vTm_, KVLEN, bx, bh, t_s);
    else         transpose_dev(ckv, vTc_, 128, bx - 18, bh, t_s);
}

// ================= attention: swapped-QK, in-register softmax =================
template <bool MASK>
__device__ __forceinline__ void attn_pass(
    const u16* __restrict__ kbase, int kstride,
    const u16* __restrict__ vbase, int vstride,
    int njt, int tid, int iq_min,
    const bf16x8* qf, u16* k_s, u16* v_s,
    f32x16& o0, f32x16& o1, float& m_run, float& l_run)
{
    const int lane = tid & 63;
    const int c31 = lane & 31;
    const int hi = lane >> 5;
    const int hi4 = hi << 2;
    const int srow = tid >> 2, ssl = tid & 3;
    const int kwa = srow * 64 + ((ssl ^ (srow & 7)) << 3);
    const int kwb = srow * 64 + (((ssl + 4) ^ (srow & 7)) << 3);
    const int iq = iq_min + c31;

    int krd[2][4];
#pragma unroll
    for (int jsub = 0; jsub < 2; ++jsub) {
        int row = jsub * 32 + c31;
#pragma unroll
        for (int ks = 0; ks < 4; ++ks)
            krd[jsub][ks] = row * 64 + (((2 * ks + hi) ^ (row & 7)) << 3);
    }
    int vrd[2][4];
#pragma unroll
    for (int half = 0; half < 2; ++half) {
        int row = half * 32 + c31;
#pragma unroll
        for (int s = 0; s < 4; ++s)
            vrd[half][s] = row * 64 + (((2 * s + hi) ^ (row & 7)) << 3);
    }

    float4 lk0, lk1, lv0, lv1;
#define AT_LOAD(T) { \
        const u16* gk = kbase + (size_t)((T) * 64 + srow) * kstride + ssl * 8; \
        lk0 = *(const float4*)gk; lk1 = *(const float4*)(gk + 32); \
        const u16* gv = vbase + (size_t)srow * vstride + (T) * 64 + ssl * 8; \
        lv0 = *(const float4*)gv; lv1 = *(const float4*)(gv + 32); }
#define AT_STORE(B) { \
        u16* kd = k_s + (B) * 4096; u16* vd = v_s + (B) * 4096; \
        *(float4*)(kd + kwa) = lk0; *(float4*)(kd + kwb) = lk1; \
        *(float4*)(vd + kwa) = lv0; *(float4*)(vd + kwb) = lv1; }

    AT_LOAD(0); AT_STORE(0);
    __syncthreads();

    for (int t = 0; t < njt; ++t) {
        const int cur = t & 1;
        if (t + 1 < njt) AT_LOAD(t + 1);
        const u16* ks_ = k_s + cur * 4096;
        const u16* vs_ = v_s + cur * 4096;

        f32x16 sA = {}, sB = {};
#pragma unroll
        for (int ks = 0; ks < 4; ++ks) {
            bf16x8 a0 = *(const bf16x8*)&ks_[krd[0][ks]];
            sA = __builtin_amdgcn_mfma_f32_32x32x16_bf16(a0, qf[ks], sA, 0, 0, 0);
        }
#pragma unroll
        for (int ks = 0; ks < 4; ++ks) {
            bf16x8 a1 = *(const bf16x8*)&ks_[krd[1][ks]];
            sB = __builtin_amdgcn_mfma_f32_32x32x16_bf16(a1, qf[ks], sB, 0, 0, 0);
        }
        if (MASK) {
            if (t * 64 + 63 > iq_min + TOTALMEM) {
#pragma unroll
                for (int r = 0; r < 16; ++r) {
                    int rj = (r & 3) + 8 * (r >> 2) + hi4;
                    if (t * 64 + rj > iq + TOTALMEM) sA[r] = -1e30f;
                    if (t * 64 + 32 + rj > iq + TOTALMEM) sB[r] = -1e30f;
                }
            }
        }
        float tmax = sA[0];
#pragma unroll
        for (int r = 1; r < 16; ++r) tmax = fmaxf(tmax, sA[r]);
#pragma unroll
        for (int r = 0; r < 16; ++r) tmax = fmaxf(tmax, sB[r]);
        tmax = fmaxf(tmax, __shfl_xor(tmax, 32));
        tmax *= 0.125f;
        if (__any(tmax > m_run + 8.0f)) {
            float m_new = fmaxf(m_run, tmax);
            float scl = __expf(m_run - m_new);
            m_run = m_new;
            l_run *= scl;
#pragma unroll
            for (int r = 0; r < 16; ++r) {
                float sc = __shfl(scl, (r & 3) + 8 * (r >> 2) + hi4);
                o0[r] *= sc; o1[r] *= sc;
            }
        }
        const float negm = -m_run;
        float ps = 0.f;
#pragma unroll
        for (int jsub = 0; jsub < 2; ++jsub) {
#pragma unroll
            for (int ksub = 0; ksub < 2; ++ksub) {
                float p0 = __expf(fmaf((jsub ? sB[ksub * 8 + 0] : sA[ksub * 8 + 0]), 0.125f, negm));
                float p1 = __expf(fmaf((jsub ? sB[ksub * 8 + 1] : sA[ksub * 8 + 1]), 0.125f, negm));
                float p2 = __expf(fmaf((jsub ? sB[ksub * 8 + 2] : sA[ksub * 8 + 2]), 0.125f, negm));
                float p3 = __expf(fmaf((jsub ? sB[ksub * 8 + 3] : sA[ksub * 8 + 3]), 0.125f, negm));
                float p4 = __expf(fmaf((jsub ? sB[ksub * 8 + 4] : sA[ksub * 8 + 4]), 0.125f, negm));
                float p5 = __expf(fmaf((jsub ? sB[ksub * 8 + 5] : sA[ksub * 8 + 5]), 0.125f, negm));
                float p6 = __expf(fmaf((jsub ? sB[ksub * 8 + 6] : sA[ksub * 8 + 6]), 0.125f, negm));
                float p7 = __expf(fmaf((jsub ? sB[ksub * 8 + 7] : sA[ksub * 8 + 7]), 0.125f, negm));
                ps += ((p0 + p1) + (p2 + p3)) + ((p4 + p5) + (p6 + p7));
                u32 X = cvtpk_bf16(p0, p1);
                u32 Z = cvtpk_bf16(p2, p3);
                u32 Y = cvtpk_bf16(p4, p5);
                u32 W = cvtpk_bf16(p6, p7);
                auto s1 = __builtin_amdgcn_permlane32_swap(X, Y, false, false);
                auto s2 = __builtin_amdgcn_permlane32_swap(Z, W, false, false);
                union { u32 w[4]; bf16x8 v; } fa;
                fa.w[0] = (u32)s1[0]; fa.w[1] = (u32)s2[0];
                fa.w[2] = (u32)s1[1]; fa.w[3] = (u32)s2[1];
                bf16x8 bv0 = *(const bf16x8*)&vs_[vrd[0][jsub * 2 + ksub]];
                bf16x8 bv1 = *(const bf16x8*)&vs_[vrd[1][jsub * 2 + ksub]];
                o0 = __builtin_amdgcn_mfma_f32_32x32x16_bf16(fa.v, bv0, o0, 0, 0, 0);
                o1 = __builtin_amdgcn_mfma_f32_32x32x16_bf16(fa.v, bv1, o1, 0, 0, 0);
            }
        }
        ps += __shfl_xor(ps, 32);
        l_run += ps;
        if (t + 1 < njt) AT_STORE(cur ^ 1);
        __syncthreads();
    }
#undef AT_LOAD
#undef AT_STORE
}

__global__ __launch_bounds__(256)
void attn_main2(const u16* __restrict__ q_bf, const u16* __restrict__ kv,
                const u16* __restrict__ vT, u16* __restrict__ out_bf) {
    __shared__ u16 k_s[2 * 4096];
    __shared__ u16 v_s[2 * 4096];
    const int it = blockIdx.x, bh = blockIdx.y;
    const int b = bh >> 3, h = bh & 7;
    const int tid = threadIdx.x;
    const int w = tid >> 6, lane = tid & 63;
    const int c31 = lane & 31, hi4 = (lane >> 5) << 2;
    const int iwmin = it * 128 + w * 32;
    const int iq = iwmin + c31;

    bf16x8 qf[4];
#pragma unroll
    for (int ks = 0; ks < 4; ++ks)
        qf[ks] = *(const bf16x8*)&q_bf[(size_t)(b * TLEN + iq) * DMODEL + h * DH + ks * 16 + hi4 * 2];

    const u16* kbase = kv + (size_t)b * KVLEN * 1024 + h * DH;
    const u16* vbase = vT + (size_t)(bh * DH) * KVLEN;
    const int njt = ((it * 128 + 767) >> 6) + 1;

    f32x16 o0 = {}, o1 = {};
    float m_run = -1e30f, l_run = 0.f;
    attn_pass<true>(kbase, 1024, vbase, KVLEN, njt, tid, iwmin, qf, k_s, v_s, o0, o1, m_run, l_run);

    float linv = 1.0f / l_run;
#pragma unroll
    for (int r = 0; r < 16; ++r) {
        int R = (r & 3) + 8 * (r >> 2) + hi4;
        float li = __shfl(linv, R);
        int i = iwmin + R;
        u16* o = out_bf + (size_t)(b * TLEN + i) * DMODEL + h * DH + c31;
        o[0]  = f2b(o0[r] * li);
        o[32] = f2b(o1[r] * li);
    }
}

// ---------------- standalone aux attention (r3 structure: own regalloc)
__global__ __launch_bounds__(256)
void attn_aux2(const u16* __restrict__ q_bf, const u16* __restrict__ kv,
               const u16* __restrict__ vTm_, const u16* __restrict__ ckv,
               const u16* __restrict__ vTc_, float* __restrict__ acc_sum) {
    __shared__ u16 k_s[2 * 4096];
    __shared__ u16 v_s[2 * 4096];
    __shared__ float red_s[4];
    const int it = blockIdx.x, bh = blockIdx.y;
    const int b = bh >> 3, h = bh & 7;
    const int tid = threadIdx.x;
    const int w = tid >> 6, lane = tid & 63;
    const int c31 = lane & 31, hi4 = (lane >> 5) << 2;
    const int iwmin = it * 128 + w * 32;
    const int iq = iwmin + c31;

    bf16x8 qf[4];
#pragma unroll
    for (int ks = 0; ks < 4; ++ks)
        qf[ks] = *(const bf16x8*)&q_bf[(size_t)(b * TLEN + iq) * DMODEL + h * DH + ks * 16 + hi4 * 2];

    f32x16 o0 = {}, o1 = {};
    float m_run = -1e30f, l_run = 0.f;
    attn_pass<false>(kv + (size_t)(b * KVLEN + 128) * 1024 + h * DH, 1024,
                     vTm_ + (size_t)(bh * DH) * KVLEN + 128, KVLEN, 8,
                     tid, 0, qf, k_s, v_s, o0, o1, m_run, l_run);
    float n0[16], n1[16];
    {
        float linv = 1.0f / l_run;
#pragma unroll
        for (int r = 0; r < 16; ++r) {
            float li = __shfl(linv, (r & 3) + 8 * (r >> 2) + hi4);
            n0[r] = o0[r] * li;
            n1[r] = o1[r] * li;
        }
    }
    f32x16 c0 = {}, c1 = {};
    m_run = -1e30f; l_run = 0.f;
    attn_pass<false>(ckv + (size_t)(b * 128) * 1024 + h * DH, 1024,
                     vTc_ + (size_t)(bh * DH) * 128, 128, 2,
                     tid, 0, qf, k_s, v_s, c0, c1, m_run, l_run);
    float lsum = 0.f;
    {
        float linv = 1.0f / l_run;
#pragma unroll
        for (int r = 0; r < 16; ++r) {
            float li = __shfl(linv, (r & 3) + 8 * (r >> 2) + hi4);
            float d0 = n0[r] - c0[r] * li;
            float d1 = n1[r] - c1[r] * li;
            lsum += d0 * d0 + d1 * d1;
        }
    }
    lsum = wave_red_sum(lsum);
    if (lane == 0) red_s[w] = lsum;
    __syncthreads();
    if (tid == 0) atomicAdd(acc_sum, red_s[0] + red_s[1] + red_s[2] + red_s[3]);
}

// ---------------- ae loss
__global__ __launch_bounds__(256)
void ae_loss_kernel(const float* __restrict__ cmem_new,
                    const float* __restrict__ mem,
                    const float* __restrict__ dw,
                    const float* __restrict__ db,
                    float* __restrict__ acc) {
    int b = blockIdx.x >> 7;
    int m0 = (blockIdx.x & 127) * 4;
    __shared__ float w_s[4][128];
    __shared__ float red_s2[4];
    int tid = threadIdx.x;
    if (tid < 128) {
#pragma unroll
        for (int mm = 0; mm < 4; ++mm) w_s[mm][tid] = dw[(m0 + mm) * 128 + tid];
    }
    __syncthreads();
    float lsum = 0.f;
#pragma unroll
    for (int rep = 0; rep < 2; ++rep) {
        int dd = tid + rep * 256;
        float a0 = 0, a1 = 0, a2 = 0, a3 = 0;
        for (int c = 0; c < 128; ++c) {
            float cv = cmem_new[(size_t)b * 65536 + c * 512 + dd];
            a0 += cv * w_s[0][c]; a1 += cv * w_s[1][c];
            a2 += cv * w_s[2][c]; a3 += cv * w_s[3][c];
        }
#pragma unroll
        for (int mm = 0; mm < 4; ++mm) {
            float a = (mm == 0) ? a0 : (mm == 1) ? a1 : (mm == 2) ? a2 : a3;
            float d = mem[(size_t)(b * 512 + m0 + mm) * 512 + dd] - (a + db[m0 + mm]);
            lsum += d * d;
        }
    }
    lsum = wave_red_sum(lsum);
    if ((tid & 63) == 0) red_s2[tid >> 6] = lsum;
    __syncthreads();
    if (tid == 0) atomicAdd(acc, red_s2[0] + red_s2[1] + red_s2[2] + red_s2[3]);
}

__global__ void finalize(const float* __restrict__ acc, float* __restrict__ out) {
    if (threadIdx.x == 0) {
        out[0] = acc[0] * (1.f / 2097152.f);
        out[1] = acc[1] * (1.f / 2097152.f);
    }
}

// ---------------- launch ----------------
extern "C" void kernel_launch(void* const* d_in, const int* in_sizes, int n_in,
                              void* d_out, int out_size, void* d_ws, size_t ws_size,
                              hipStream_t stream) {
    const float* x      = (const float*)d_in[0];
    const float* mem    = (const float*)d_in[1];
    const float* cmem   = (const float*)d_in[2];
    const float* Wq     = (const float*)d_in[3];
    const float* Wkv    = (const float*)d_in[4];
    const float* Wo     = (const float*)d_in[5];
    const float* bo     = (const float*)d_in[6];
    const float* conv_w = (const float*)d_in[7];
    const float* conv_b = (const float*)d_in[8];
    const float* deconv_w = (const float*)d_in[9];
    const float* deconv_b = (const float*)d_in[10];
    float* out = (float*)d_out;

    char* w = (char*)d_ws;
    auto alloc = [&](size_t bytes) { char* p = w; w += (bytes + 255) & ~255ull; return p; };
    u16* Wq_bf   = (u16*)alloc(262144 * 2);
    u16* Wkv_bf  = (u16*)alloc(524288 * 2);
    u16* Wo_bf   = (u16*)alloc(262144 * 2);
    u16* cw2_bf  = (u16*)alloc(1048576 * 2);
    u16* kvin_bf = (u16*)alloc(4718592 * 2);
    u16* q_bf    = (u16*)alloc(2097152 * 2);
    u16* kv_bf   = (u16*)alloc(9437184 * 2);
    u16* comp_bf = (u16*)alloc(524288 * 2);
    u16* ckv_bf  = (u16*)alloc(1048576 * 2);
    u16* vTm     = (u16*)alloc(4718592 * 2);
    u16* vTc     = (u16*)alloc(524288 * 2);
    u16* attn_bf = (u16*)alloc(2097152 * 2);
    float* part  = (float*)alloc(8 * 524288 * 4);
    float* accs  = (float*)alloc(256);

    float* logits_o  = out;
    float* newmem_o  = out + 2097152;
    float* newcmem_o = out + 4194304;
    float* scalars_o = out + 4718592;

    // 1. prep: kvin + new_mem + weight converts + acc zero
    prep_kernel<<<6656, 256, 0, stream>>>(x, mem, cmem, Wq, Wkv, Wo, conv_w,
                                          kvin_bf, Wq_bf, Wkv_bf, Wo_bf, cw2_bf,
                                          newmem_o, accs);

    // 2. fused q + kv + conv GEMMs (960 blocks)
    gemm3<<<960, 256, 0, stream>>>(kvin_bf, Wq_bf, Wkv_bf, cw2_bf, q_bf, kv_bf, part);

    // 3. conv split-K reduce -> new_cmem (f32) + comp (bf16)
    conv_reduce<<<512, 256, 0, stream>>>(part, conv_b, newcmem_o, comp_bf);

    // 4. ckv projection
    gemm_full<<<dim3(8, 8), 256, 0, stream>>>(comp_bf, 512, 1024, 0, Wkv_bf, 512, 512,
                                              nullptr, ckv_bf, 1024, nullptr);

    // 5. both V transposes
    transpose2<<<dim3(20, 64), 256, 0, stream>>>(kv_bf, vTm, ckv_bf, vTc);

    // 6. main causal attention
    attn_main2<<<dim3(4, 64), 256, 0, stream>>>(q_bf, kv_bf, vTm, attn_bf);

    // 7. Wo output projection
    gemm_full<<<dim3(32, 4), 256, 0, stream>>>(attn_bf, 512, 4096, 0, Wo_bf, 512, 512,
                                               logits_o, nullptr, 512, bo);

    // 8. aux loss attention (standalone: own register allocation)
    attn_aux2<<<dim3(4, 64), 256, 0, stream>>>(q_bf, kv_bf, vTm, ckv_bf, vTc, accs);

    // 9. ae loss
    ae_loss_kernel<<<1024, 256, 0, stream>>>(newcmem_o, mem, deconv_w, deconv_b, accs + 1);

    // 10. finalize scalars
    finalize<<<1, 64, 0, stream>>>(accs, scalars_o);
}

// Round 6
// 164.445 us; speedup vs baseline: 1.8564x; 1.0022x over previous
//
#include <hip/hip_runtime.h>

typedef __bf16 bf16x8 __attribute__((ext_vector_type(8)));
typedef float f32x4 __attribute__((ext_vector_type(4)));
typedef float f32x16 __attribute__((ext_vector_type(16)));
typedef unsigned short u16;
typedef unsigned int u32;

#define TLEN 512
#define DMODEL 512
#define DH 64
#define KVLEN 1152
#define TOTALMEM 640

__device__ inline u16 f2b(float f) {
    union { float f; u32 u; } x; x.f = f;
    u32 u = x.u;
    return (u16)((u + 0x7FFFu + ((u >> 16) & 1u)) >> 16);
}

__device__ inline float wave_red_sum(float v) {
#pragma unroll
    for (int off = 1; off < 64; off <<= 1) v += __shfl_xor(v, off);
    return v;
}

__device__ inline void gload16(const u16* g, u16* l) {
    __builtin_amdgcn_global_load_lds((const __attribute__((address_space(1))) void*)g,
                                     (__attribute__((address_space(3))) void*)l, 16, 0, 0);
}

__device__ __forceinline__ u32 cvtpk_bf16(float lo, float hi) {
    u32 r;
    asm("v_cvt_pk_bf16_f32 %0, %1, %2" : "=v"(r) : "v"(lo), "v"(hi));
    return r;
}

// ---------------- fused prep: kvin build + new_mem passthrough + weight converts + acc zero
__global__ __launch_bounds__(256)
void prep_kernel(const float* __restrict__ x, const float* __restrict__ mem,
                 const float* __restrict__ cmem, const float* __restrict__ Wq,
                 const float* __restrict__ Wkv, const float* __restrict__ Wo,
                 const float* __restrict__ cw,
                 u16* __restrict__ kvin, u16* __restrict__ wq_b, u16* __restrict__ wkv_b,
                 u16* __restrict__ wo_b, u16* __restrict__ cw2,
                 float* __restrict__ newmem, float* __restrict__ accs) {
    int idx = blockIdx.x * 256 + threadIdx.x;
    if (idx == 0) { accs[0] = 0.f; accs[1] = 0.f; accs[2] = 0.f; accs[3] = 0.f; }
    int e = idx * 4;
    float4 v;
    u16* o;
    if (e < 4718592) {
        int row = e >> 9, col = e & 511;
        int b = row / KVLEN, p = row - b * KVLEN;
        const float* src;
        if (p < 128)       src = cmem + ((size_t)(b * 128 + p)) * 512 + col;
        else if (p < 640)  src = mem  + ((size_t)(b * 512 + (p - 128))) * 512 + col;
        else               src = x    + ((size_t)(b * 512 + (p - 640))) * 512 + col;
        v = *(const float4*)src;
        o = kvin + e;
        if (p >= 640)
            *(float4*)(newmem + ((size_t)(b * 512 + (p - 640)) * 512 + col)) = v;
    } else if (e < 4980736) {
        int t = e - 4718592; v = *(const float4*)(Wq + t); o = wq_b + t;
    } else if (e < 5505024) {
        int t = e - 4980736; v = *(const float4*)(Wkv + t); o = wkv_b + t;
    } else if (e < 5767168) {
        int t = e - 5505024; v = *(const float4*)(Wo + t); o = wo_b + t;
    } else {
        int t = e - 5767168;
        int oo = t >> 11, rem = t & 2047, tt = rem >> 9, ii = rem & 511;
        const float* s0 = cw + oo * 2048 + tt;
        v.x = s0[(ii + 0) * 4]; v.y = s0[(ii + 1) * 4];
        v.z = s0[(ii + 2) * 4]; v.w = s0[(ii + 3) * 4];
        o = cw2 + t;
    }
    o[0] = f2b(v.x); o[1] = f2b(v.y); o[2] = f2b(v.z); o[3] = f2b(v.w);
}

// ---------------- generic bf16 MFMA GEMM device body (m97 staging)
__device__ __forceinline__ void gemm_dev(
    const u16* __restrict__ A, int lda, int rowsPerB, long long bstride,
    const u16* __restrict__ Bt, int ldb, int Kb,
    float* __restrict__ Cpart, int partStride,
    float* __restrict__ Cf, u16* __restrict__ Cb, int ldc,
    const float* __restrict__ bias,
    int bx, int by, int bz, u16* As, u16* Bs) {
    const int tid = threadIdx.x;
    const int lane = tid & 63, wave = tid >> 6;
    const int wr = (wave >> 1) * 64, wc = (wave & 1) * 64;
    const int fr = lane & 15, fg = lane >> 4;
    const int arow0 = bx * 128;
    const int brow0 = by * 128;
    const int k0start = bz * Kb;

    const int lrow = lane >> 2;
    const int lcol = (lane & 3) * 8;
    const u16* gA[2]; const u16* gB[2];
#pragma unroll
    for (int i = 0; i < 2; ++i) {
        int r = wave * 32 + i * 16 + lrow;
        int gr = arow0 + r;
        int bb = gr / rowsPerB;
        int lr = gr - bb * rowsPerB;
        gA[i] = A + (size_t)bb * bstride + (size_t)lr * lda + k0start + lcol;
        gB[i] = Bt + (size_t)(brow0 + r) * ldb + k0start + lcol;
    }
    u16* lA0 = &As[(wave * 32) * 32];
    u16* lA1 = &As[(wave * 32 + 16) * 32];
    u16* lB0 = &Bs[(wave * 32) * 32];
    u16* lB1 = &Bs[(wave * 32 + 16) * 32];

    f32x4 acc[4][4] = {};
    for (int k = 0; k < Kb; k += 32) {
        __syncthreads();
        gload16(gA[0] + k, lA0);
        gload16(gA[1] + k, lA1);
        gload16(gB[0] + k, lB0);
        gload16(gB[1] + k, lB1);
        __syncthreads();
        bf16x8 af[4], bfr[4];
#pragma unroll
        for (int m = 0; m < 4; ++m) af[m] = *(bf16x8*)&As[(wr + m * 16 + fr) * 32 + fg * 8];
#pragma unroll
        for (int n = 0; n < 4; ++n) bfr[n] = *(bf16x8*)&Bs[(wc + n * 16 + fr) * 32 + fg * 8];
#pragma unroll
        for (int m = 0; m < 4; ++m)
#pragma unroll
            for (int n = 0; n < 4; ++n)
                acc[m][n] = __builtin_amdgcn_mfma_f32_16x16x32_bf16(af[m], bfr[n], acc[m][n], 0, 0, 0);
    }

#pragma unroll
    for (int m = 0; m < 4; ++m)
#pragma unroll
        for (int n = 0; n < 4; ++n)
#pragma unroll
            for (int r = 0; r < 4; ++r) {
                int row = arow0 + wr + m * 16 + fg * 4 + r;
                int col = brow0 + wc + n * 16 + fr;
                float v = acc[m][n][r];
                if (Cpart) {
                    Cpart[(size_t)bz * partStride + (size_t)row * ldc + col] = v;
                } else {
                    if (bias) v += bias[col];
                    if (Cf) Cf[(size_t)row * ldc + col] = v;
                    if (Cb) Cb[(size_t)row * ldc + col] = f2b(v);
                }
            }
}

// ---------------- fused q + kv + conv GEMMs (one 832-block dispatch, conv split-K=4)
__global__ __launch_bounds__(256)
void gemm3(const u16* __restrict__ kvin, const u16* __restrict__ wq,
           const u16* __restrict__ wkv, const u16* __restrict__ cw2,
           u16* __restrict__ q_bf, u16* __restrict__ kv_bf, float* __restrict__ part) {
    __shared__ u16 As[128 * 32];
    __shared__ u16 Bs[128 * 32];
    int id = blockIdx.x;
    if (id < 128) {
        gemm_dev(kvin + 327680, 512, 512, 589824, wq, 512, 512,
                 nullptr, 0, nullptr, q_bf, 512, nullptr,
                 id & 31, id >> 5, 0, As, Bs);
    } else if (id < 704) {
        int t = id - 128;
        gemm_dev(kvin, 512, 9216, 0, wkv, 512, 512,
                 nullptr, 0, nullptr, kv_bf, 1024, nullptr,
                 t % 72, t / 72, 0, As, Bs);
    } else {
        int t = id - 704;   // 128 blocks: 8 x 4 x 4 split-K
        gemm_dev(kvin + 65536, 2048, 128, 589824, cw2, 2048, 512,
                 part, 524288, nullptr, nullptr, 512, nullptr,
                 t & 7, (t >> 3) & 3, t >> 5, As, Bs);
    }
}

// ---------------- standalone GEMM (ckv)
__global__ __launch_bounds__(256)
void gemm_full(const u16* __restrict__ A, int lda, int rowsPerB, long long bstride,
               const u16* __restrict__ Bt, int ldb, int Kb,
               float* __restrict__ Cf, u16* __restrict__ Cb, int ldc,
               const float* __restrict__ bias) {
    __shared__ u16 As[128 * 32];
    __shared__ u16 Bs[128 * 32];
    gemm_dev(A, lda, rowsPerB, bstride, Bt, ldb, Kb, nullptr, 0, Cf, Cb, ldc,
             bias, blockIdx.x, blockIdx.y, 0, As, Bs);
}

// ---------------- split-K reduce for conv (4 slices)
__global__ __launch_bounds__(256)
void conv_reduce(const float* __restrict__ part, const float* __restrict__ cb,
                 float* __restrict__ outf, u16* __restrict__ outb) {
    int idx = (blockIdx.x * 256 + threadIdx.x) * 4;
    float4 s = *(const float4*)(part + idx);
#pragma unroll
    for (int sp = 1; sp < 4; ++sp) {
        float4 p = *(const float4*)(part + (size_t)sp * 524288 + idx);
        s.x += p.x; s.y += p.y; s.z += p.z; s.w += p.w;
    }
    float4 bb = *(const float4*)(cb + (idx & 511));
    s.x += bb.x; s.y += bb.y; s.z += bb.z; s.w += bb.w;
    *(float4*)(outf + idx) = s;
    outb[idx + 0] = f2b(s.x); outb[idx + 1] = f2b(s.y);
    outb[idx + 2] = f2b(s.z); outb[idx + 3] = f2b(s.w);
}

// ---------------- V transposes (vTm + vTc in one dispatch)
__device__ __forceinline__ void transpose_dev(const u16* __restrict__ kv,
                                              u16* __restrict__ vT, int rowsPerB,
                                              int jt, int bh, u16* t_s) {
    int b = bh >> 3, h = bh & 7;
    int tid = threadIdx.x;
    int jr = tid >> 2, c0 = (tid & 3) * 16;
    const u16* g = kv + (size_t)(b * rowsPerB + jt * 64 + jr) * 1024 + 512 + h * DH + c0;
#pragma unroll
    for (int u = 0; u < 16; ++u) t_s[jr * 65 + c0 + u] = g[u];
    __syncthreads();
    int dh = tid >> 2, j0 = (tid & 3) * 16;
    union { u16 us[8]; bf16x8 v8; } o1, o2;
#pragma unroll
    for (int u = 0; u < 8; ++u) {
        o1.us[u] = t_s[(j0 + u) * 65 + dh];
        o2.us[u] = t_s[(j0 + 8 + u) * 65 + dh];
    }
    u16* o = vT + (size_t)(bh * DH + dh) * rowsPerB + jt * 64 + j0;
    *(bf16x8*)o = o1.v8;
    *(bf16x8*)(o + 8) = o2.v8;
}

__global__ __launch_bounds__(256)
void transpose2(const u16* __restrict__ kv, u16* __restrict__ vTm_,
                const u16* __restrict__ ckv, u16* __restrict__ vTc_) {
    __shared__ u16 t_s[64 * 65];
    int bx = blockIdx.x, bh = blockIdx.y;
    if (bx < 18) transpose_dev(kv, vTm_, KVLEN, bx, bh, t_s);
    else         transpose_dev(ckv, vTc_, 128, bx - 18, bh, t_s);
}

// ================= attention: swapped-QK, in-register softmax =================
template <bool MASK>
__device__ __forceinline__ void attn_pass(
    const u16* __restrict__ kbase, int kstride,
    const u16* __restrict__ vbase, int vstride,
    int njt, int tid, int iq_min,
    const bf16x8* qf, u16* k_s, u16* v_s,
    f32x16& o0, f32x16& o1, float& m_run, float& l_run)
{
    const int lane = tid & 63;
    const int c31 = lane & 31;
    const int hi = lane >> 5;
    const int hi4 = hi << 2;
    const int srow = tid >> 2, ssl = tid & 3;
    const int kwa = srow * 64 + ((ssl ^ (srow & 7)) << 3);
    const int kwb = srow * 64 + (((ssl + 4) ^ (srow & 7)) << 3);
    const int iq = iq_min + c31;

    int krd[2][4];
#pragma unroll
    for (int jsub = 0; jsub < 2; ++jsub) {
        int row = jsub * 32 + c31;
#pragma unroll
        for (int ks = 0; ks < 4; ++ks)
            krd[jsub][ks] = row * 64 + (((2 * ks + hi) ^ (row & 7)) << 3);
    }
    int vrd[2][4];
#pragma unroll
    for (int half = 0; half < 2; ++half) {
        int row = half * 32 + c31;
#pragma unroll
        for (int s = 0; s < 4; ++s)
            vrd[half][s] = row * 64 + (((2 * s + hi) ^ (row & 7)) << 3);
    }

    float4 lk0, lk1, lv0, lv1;
#define AT_LOAD(T) { \
        const u16* gk = kbase + (size_t)((T) * 64 + srow) * kstride + ssl * 8; \
        lk0 = *(const float4*)gk; lk1 = *(const float4*)(gk + 32); \
        const u16* gv = vbase + (size_t)srow * vstride + (T) * 64 + ssl * 8; \
        lv0 = *(const float4*)gv; lv1 = *(const float4*)(gv + 32); }
#define AT_STORE(B) { \
        u16* kd = k_s + (B) * 4096; u16* vd = v_s + (B) * 4096; \
        *(float4*)(kd + kwa) = lk0; *(float4*)(kd + kwb) = lk1; \
        *(float4*)(vd + kwa) = lv0; *(float4*)(vd + kwb) = lv1; }

    AT_LOAD(0); AT_STORE(0);
    __syncthreads();

    for (int t = 0; t < njt; ++t) {
        const int cur = t & 1;
        if (t + 1 < njt) AT_LOAD(t + 1);
        const u16* ks_ = k_s + cur * 4096;
        const u16* vs_ = v_s + cur * 4096;

        f32x16 sA = {}, sB = {};
#pragma unroll
        for (int ks = 0; ks < 4; ++ks) {
            bf16x8 a0 = *(const bf16x8*)&ks_[krd[0][ks]];
            sA = __builtin_amdgcn_mfma_f32_32x32x16_bf16(a0, qf[ks], sA, 0, 0, 0);
        }
#pragma unroll
        for (int ks = 0; ks < 4; ++ks) {
            bf16x8 a1 = *(const bf16x8*)&ks_[krd[1][ks]];
            sB = __builtin_amdgcn_mfma_f32_32x32x16_bf16(a1, qf[ks], sB, 0, 0, 0);
        }
        if (MASK) {
            if (t * 64 + 63 > iq_min + TOTALMEM) {
#pragma unroll
                for (int r = 0; r < 16; ++r) {
                    int rj = (r & 3) + 8 * (r >> 2) + hi4;
                    if (t * 64 + rj > iq + TOTALMEM) sA[r] = -1e30f;
                    if (t * 64 + 32 + rj > iq + TOTALMEM) sB[r] = -1e30f;
                }
            }
        }
        float tmax = sA[0];
#pragma unroll
        for (int r = 1; r < 16; ++r) tmax = fmaxf(tmax, sA[r]);
#pragma unroll
        for (int r = 0; r < 16; ++r) tmax = fmaxf(tmax, sB[r]);
        tmax = fmaxf(tmax, __shfl_xor(tmax, 32));
        tmax *= 0.125f;
        if (__any(tmax > m_run + 8.0f)) {
            float m_new = fmaxf(m_run, tmax);
            float scl = __expf(m_run - m_new);
            m_run = m_new;
            l_run *= scl;
#pragma unroll
            for (int r = 0; r < 16; ++r) {
                float sc = __shfl(scl, (r & 3) + 8 * (r >> 2) + hi4);
                o0[r] *= sc; o1[r] *= sc;
            }
        }
        const float negm = -m_run;
        float ps = 0.f;
#pragma unroll
        for (int jsub = 0; jsub < 2; ++jsub) {
#pragma unroll
            for (int ksub = 0; ksub < 2; ++ksub) {
                float p0 = __expf(fmaf((jsub ? sB[ksub * 8 + 0] : sA[ksub * 8 + 0]), 0.125f, negm));
                float p1 = __expf(fmaf((jsub ? sB[ksub * 8 + 1] : sA[ksub * 8 + 1]), 0.125f, negm));
                float p2 = __expf(fmaf((jsub ? sB[ksub * 8 + 2] : sA[ksub * 8 + 2]), 0.125f, negm));
                float p3 = __expf(fmaf((jsub ? sB[ksub * 8 + 3] : sA[ksub * 8 + 3]), 0.125f, negm));
                float p4 = __expf(fmaf((jsub ? sB[ksub * 8 + 4] : sA[ksub * 8 + 4]), 0.125f, negm));
                float p5 = __expf(fmaf((jsub ? sB[ksub * 8 + 5] : sA[ksub * 8 + 5]), 0.125f, negm));
                float p6 = __expf(fmaf((jsub ? sB[ksub * 8 + 6] : sA[ksub * 8 + 6]), 0.125f, negm));
                float p7 = __expf(fmaf((jsub ? sB[ksub * 8 + 7] : sA[ksub * 8 + 7]), 0.125f, negm));
                ps += ((p0 + p1) + (p2 + p3)) + ((p4 + p5) + (p6 + p7));
                u32 X = cvtpk_bf16(p0, p1);
                u32 Z = cvtpk_bf16(p2, p3);
                u32 Y = cvtpk_bf16(p4, p5);
                u32 W = cvtpk_bf16(p6, p7);
                auto s1 = __builtin_amdgcn_permlane32_swap(X, Y, false, false);
                auto s2 = __builtin_amdgcn_permlane32_swap(Z, W, false, false);
                union { u32 w[4]; bf16x8 v; } fa;
                fa.w[0] = (u32)s1[0]; fa.w[1] = (u32)s2[0];
                fa.w[2] = (u32)s1[1]; fa.w[3] = (u32)s2[1];
                bf16x8 bv0 = *(const bf16x8*)&vs_[vrd[0][jsub * 2 + ksub]];
                bf16x8 bv1 = *(const bf16x8*)&vs_[vrd[1][jsub * 2 + ksub]];
                o0 = __builtin_amdgcn_mfma_f32_32x32x16_bf16(fa.v, bv0, o0, 0, 0, 0);
                o1 = __builtin_amdgcn_mfma_f32_32x32x16_bf16(fa.v, bv1, o1, 0, 0, 0);
            }
        }
        ps += __shfl_xor(ps, 32);
        l_run += ps;
        if (t + 1 < njt) AT_STORE(cur ^ 1);
        __syncthreads();
    }
#undef AT_LOAD
#undef AT_STORE
}

// ---------------- fused main + aux attention (same register class; 512 blocks -> 2 waves/SIMD)
__global__ __launch_bounds__(256)
void attn_fused(const u16* __restrict__ q_bf, const u16* __restrict__ kv,
                const u16* __restrict__ vTm_, const u16* __restrict__ ckv,
                const u16* __restrict__ vTc_, u16* __restrict__ out_bf,
                float* __restrict__ acc_sum) {
    __shared__ u16 k_s[2 * 4096];
    __shared__ u16 v_s[2 * 4096];
    __shared__ float red_s[4];
    const int id = blockIdx.x;
    const int tid = threadIdx.x;
    const int w = tid >> 6, lane = tid & 63;
    const int c31 = lane & 31, hi4 = (lane >> 5) << 2;

    if (id < 256) {
        // ---- main causal attention
        const int it = id & 3, bh = id >> 2;
        const int b = bh >> 3, h = bh & 7;
        const int iwmin = it * 128 + w * 32;
        const int iq = iwmin + c31;

        bf16x8 qf[4];
#pragma unroll
        for (int ks = 0; ks < 4; ++ks)
            qf[ks] = *(const bf16x8*)&q_bf[(size_t)(b * TLEN + iq) * DMODEL + h * DH + ks * 16 + hi4 * 2];

        const u16* kbase = kv + (size_t)b * KVLEN * 1024 + h * DH;
        const u16* vbase = vTm_ + (size_t)(bh * DH) * KVLEN;
        const int njt = ((it * 128 + 767) >> 6) + 1;

        f32x16 o0 = {}, o1 = {};
        float m_run = -1e30f, l_run = 0.f;
        attn_pass<true>(kbase, 1024, vbase, KVLEN, njt, tid, iwmin, qf, k_s, v_s, o0, o1, m_run, l_run);

        float linv = 1.0f / l_run;
#pragma unroll
        for (int r = 0; r < 16; ++r) {
            int R = (r & 3) + 8 * (r >> 2) + hi4;
            float li = __shfl(linv, R);
            int i = iwmin + R;
            u16* o = out_bf + (size_t)(b * TLEN + i) * DMODEL + h * DH + c31;
            o[0]  = f2b(o0[r] * li);
            o[32] = f2b(o1[r] * li);
        }
    } else {
        // ---- aux loss attention
        const int t2 = id - 256;
        const int it = t2 & 3, bh = t2 >> 2;
        const int b = bh >> 3, h = bh & 7;
        const int iwmin = it * 128 + w * 32;
        const int iq = iwmin + c31;

        bf16x8 qf[4];
#pragma unroll
        for (int ks = 0; ks < 4; ++ks)
            qf[ks] = *(const bf16x8*)&q_bf[(size_t)(b * TLEN + iq) * DMODEL + h * DH + ks * 16 + hi4 * 2];

        f32x16 o0 = {}, o1 = {};
        float m_run = -1e30f, l_run = 0.f;
        attn_pass<false>(kv + (size_t)(b * KVLEN + 128) * 1024 + h * DH, 1024,
                         vTm_ + (size_t)(bh * DH) * KVLEN + 128, KVLEN, 8,
                         tid, 0, qf, k_s, v_s, o0, o1, m_run, l_run);
        float n0[16], n1[16];
        {
            float linv = 1.0f / l_run;
#pragma unroll
            for (int r = 0; r < 16; ++r) {
                float li = __shfl(linv, (r & 3) + 8 * (r >> 2) + hi4);
                n0[r] = o0[r] * li;
                n1[r] = o1[r] * li;
            }
        }
        f32x16 c0 = {}, c1 = {};
        m_run = -1e30f; l_run = 0.f;
        attn_pass<false>(ckv + (size_t)(b * 128) * 1024 + h * DH, 1024,
                         vTc_ + (size_t)(bh * DH) * 128, 128, 2,
                         tid, 0, qf, k_s, v_s, c0, c1, m_run, l_run);
        float lsum = 0.f;
        {
            float linv = 1.0f / l_run;
#pragma unroll
            for (int r = 0; r < 16; ++r) {
                float li = __shfl(linv, (r & 3) + 8 * (r >> 2) + hi4);
                float d0 = n0[r] - c0[r] * li;
                float d1 = n1[r] - c1[r] * li;
                lsum += d0 * d0 + d1 * d1;
            }
        }
        lsum = wave_red_sum(lsum);
        if (lane == 0) red_s[w] = lsum;
        __syncthreads();
        if (tid == 0) atomicAdd(acc_sum, red_s[0] + red_s[1] + red_s[2] + red_s[3]);
    }
}

// ---------------- fused tail: Wo GEMM + ae loss + counter finalize (light branches only)
__global__ __launch_bounds__(256)
void tail2(const u16* __restrict__ attn_bf, const u16* __restrict__ wo_b,
           const float* __restrict__ bo, float* __restrict__ logits,
           const float* __restrict__ cmem_new, const float* __restrict__ mem,
           const float* __restrict__ dw, const float* __restrict__ db,
           float* __restrict__ accs, float* __restrict__ scal_out) {
    __shared__ __align__(16) char smem[16400];
    const int id = blockIdx.x;
    const int tid = threadIdx.x;

    if (id < 128) {
        // ---- Wo output projection (VGPR ~72 class)
        u16* As = (u16*)smem;
        u16* Bs = (u16*)(smem + 8192);
        gemm_dev(attn_bf, 512, 4096, 0, wo_b, 512, 512,
                 nullptr, 0, logits, nullptr, 512, bo, id & 31, id >> 5, 0, As, Bs);
        return;
    }
    // ---- ae loss (VGPR ~48 class)
    float* w_s = (float*)smem;                 // [4][128]
    float* red2 = (float*)(smem + 2048);
    const int t3 = id - 128;
    const int b = t3 >> 7;
    const int m0 = (t3 & 127) * 4;
    if (tid < 128) {
#pragma unroll
        for (int mm = 0; mm < 4; ++mm) w_s[mm * 128 + tid] = dw[(m0 + mm) * 128 + tid];
    }
    __syncthreads();
    float lsum = 0.f;
#pragma unroll
    for (int rep = 0; rep < 2; ++rep) {
        int dd = tid + rep * 256;
        float a0 = 0, a1 = 0, a2 = 0, a3 = 0;
        for (int c = 0; c < 128; ++c) {
            float cv = cmem_new[(size_t)b * 65536 + c * 512 + dd];
            a0 += cv * w_s[0 * 128 + c]; a1 += cv * w_s[1 * 128 + c];
            a2 += cv * w_s[2 * 128 + c]; a3 += cv * w_s[3 * 128 + c];
        }
#pragma unroll
        for (int mm = 0; mm < 4; ++mm) {
            float a = (mm == 0) ? a0 : (mm == 1) ? a1 : (mm == 2) ? a2 : a3;
            float d = mem[(size_t)(b * 512 + m0 + mm) * 512 + dd] - (a + db[m0 + mm]);
            lsum += d * d;
        }
    }
    lsum = wave_red_sum(lsum);
    if ((tid & 63) == 0) red2[tid >> 6] = lsum;
    __syncthreads();
    if (tid == 0) {
        atomicAdd(accs + 1, red2[0] + red2[1] + red2[2] + red2[3]);
        __threadfence();
        u32 c = atomicAdd((u32*)(accs + 2), 1u);
        if (c == 1023u) {   // last ae block: aux sum landed in prior kernel (stream order)
            float a0 = atomicAdd(accs + 0, 0.f);
            float a1 = atomicAdd(accs + 1, 0.f);
            scal_out[0] = a0 * (1.f / 2097152.f);
            scal_out[1] = a1 * (1.f / 2097152.f);
        }
    }
}

// ---------------- launch ----------------
extern "C" void kernel_launch(void* const* d_in, const int* in_sizes, int n_in,
                              void* d_out, int out_size, void* d_ws, size_t ws_size,
                              hipStream_t stream) {
    const float* x      = (const float*)d_in[0];
    const float* mem    = (const float*)d_in[1];
    const float* cmem   = (const float*)d_in[2];
    const float* Wq     = (const float*)d_in[3];
    const float* Wkv    = (const float*)d_in[4];
    const float* Wo     = (const float*)d_in[5];
    const float* bo     = (const float*)d_in[6];
    const float* conv_w = (const float*)d_in[7];
    const float* conv_b = (const float*)d_in[8];
    const float* deconv_w = (const float*)d_in[9];
    const float* deconv_b = (const float*)d_in[10];
    float* out = (float*)d_out;

    char* w = (char*)d_ws;
    auto alloc = [&](size_t bytes) { char* p = w; w += (bytes + 255) & ~255ull; return p; };
    u16* Wq_bf   = (u16*)alloc(262144 * 2);
    u16* Wkv_bf  = (u16*)alloc(524288 * 2);
    u16* Wo_bf   = (u16*)alloc(262144 * 2);
    u16* cw2_bf  = (u16*)alloc(1048576 * 2);
    u16* kvin_bf = (u16*)alloc(4718592 * 2);
    u16* q_bf    = (u16*)alloc(2097152 * 2);
    u16* kv_bf   = (u16*)alloc(9437184 * 2);
    u16* comp_bf = (u16*)alloc(524288 * 2);
    u16* ckv_bf  = (u16*)alloc(1048576 * 2);
    u16* vTm     = (u16*)alloc(4718592 * 2);
    u16* vTc     = (u16*)alloc(524288 * 2);
    u16* attn_bf = (u16*)alloc(2097152 * 2);
    float* part  = (float*)alloc(4 * 524288 * 4);
    float* accs  = (float*)alloc(256);

    float* logits_o  = out;
    float* newmem_o  = out + 2097152;
    float* newcmem_o = out + 4194304;
    float* scalars_o = out + 4718592;

    // 1. prep: kvin + new_mem + weight converts + acc/counter zero
    prep_kernel<<<6656, 256, 0, stream>>>(x, mem, cmem, Wq, Wkv, Wo, conv_w,
                                          kvin_bf, Wq_bf, Wkv_bf, Wo_bf, cw2_bf,
                                          newmem_o, accs);

    // 2. fused q + kv + conv GEMMs (832 blocks, conv split-K=4)
    gemm3<<<832, 256, 0, stream>>>(kvin_bf, Wq_bf, Wkv_bf, cw2_bf, q_bf, kv_bf, part);

    // 3. conv split-K reduce -> new_cmem (f32) + comp (bf16)
    conv_reduce<<<512, 256, 0, stream>>>(part, conv_b, newcmem_o, comp_bf);

    // 4. ckv projection
    gemm_full<<<dim3(8, 8), 256, 0, stream>>>(comp_bf, 512, 1024, 0, Wkv_bf, 512, 512,
                                              nullptr, ckv_bf, 1024, nullptr);

    // 5. both V transposes
    transpose2<<<dim3(20, 64), 256, 0, stream>>>(kv_bf, vTm, ckv_bf, vTc);

    // 6. fused main + aux attention (512 blocks -> 2 waves/SIMD)
    attn_fused<<<512, 256, 0, stream>>>(q_bf, kv_bf, vTm, ckv_bf, vTc, attn_bf, accs);

    // 7. fused tail: Wo GEMM + ae loss + finalize
    tail2<<<1152, 256, 0, stream>>>(attn_bf, Wo_bf, bo, logits_o,
                                    newcmem_o, mem, deconv_w, deconv_b,
                                    accs, scalars_o);
}